// Round 6
// baseline (251.050 us; speedup 1.0000x reference)
//
#include <hip/hip_runtime.h>

// Fused attention block for MI355X (gfx950).
// x[4096,768] fp32 -> QKV bf16 GEMM -> flash attention (12 heads, D=64) -> proj GEMM -> fp32 out.
// MFMA v_mfma_f32_16x16x32_bf16 verified layouts:
//   A-frag: m=lane&15, k=quad*8+j ; B-frag: n=lane&15, k=quad*8+j ; C/D: row=quad*4+reg, col=lane&15.
// flash_attn v7 = v4 (proven 96.7us) with V moved from LDS to REGISTERS:
//   K: LDS double-buffered via global_load_lds + barriers (unchanged latency-hiding machinery).
//   V: asm-volatile global_load_dwordx4 into ping-pong register banks, 2x-unrolled loop.
//     - asm volatile defeats the rematerialization that killed v6 (VGPR=60 proved the compiler
//       reloaded V at the use site, recreating v5's zero-slack latency-bound pattern).
//     - ping-pong banks (never read the bank being loaded) avoid copies that would read
//       in-flight asm destinations; the next __syncthreads' vmcnt(0) drain lands the bank.
//   LDS traffic/block-iter: 96 KB -> 56 KB (v4 measured ~93% of the 85 B/cyc ds ceiling).
// Softmax is UN-NORMALIZED (no running max: logits bounded, exp2 arg << 128); lsum reduced
// once in the epilogue. Q is pre-scaled by 8*log2(e) so p = exp2(s) directly (raw v_exp_f32).

typedef short bf16x8 __attribute__((ext_vector_type(8)));
typedef float f32x4 __attribute__((ext_vector_type(4)));
typedef unsigned short u16;
typedef unsigned int u32;

__device__ __forceinline__ u16 f2bf(float f) {
  u32 u = __float_as_uint(f);
  u = (u + 0x7fffu + ((u >> 16) & 1u)) >> 16;  // RNE
  return (u16)u;
}

// pack two fp32 -> bf16 pair (RNE), [a low, b high]; v_perm_b32 grabs both high halves
__device__ __forceinline__ u32 packbf(float a, float b) {
  u32 ua = __float_as_uint(a), ub = __float_as_uint(b);
  ua += 0x7fffu + ((ua >> 16) & 1u);
  ub += 0x7fffu + ((ub >> 16) & 1u);
  return __builtin_amdgcn_perm(ub, ua, 0x07060302);
}

__device__ __forceinline__ void gload16(const void* g, void* l) {
  __builtin_amdgcn_global_load_lds(
      (const __attribute__((address_space(1))) unsigned int*)g,
      (__attribute__((address_space(3))) unsigned int*)l, 16, 0, 0);
}

// opaque 16B global->VGPR load: cannot be rematerialized/sunk by the compiler.
// The result is NOT ready until a vmcnt wait; callers rely on the next __syncthreads
// (which drains vmcnt to 0 -- a HW counter, covers asm-issued loads) before reading.
__device__ __forceinline__ void gld128(bf16x8& d, const u16* p) {
  asm volatile("global_load_dwordx4 %0, %1, off" : "=v"(d) : "v"(p));
}

// ---------------- fused fp32 -> bf16 cast of x, qkv_w, proj_w (one launch) ----------------
__global__ void cast3(const float* __restrict__ a, int na4,
                      const float* __restrict__ b, int nb4,
                      const float* __restrict__ c, int nc4,
                      u16* __restrict__ oa, u16* __restrict__ obp, u16* __restrict__ oc) {
  int i = blockIdx.x * blockDim.x + threadIdx.x;
  const float* src;
  u16* dst;
  int j = i;
  if (i < na4) { src = a; dst = oa; }
  else if (i < na4 + nb4) { src = b; dst = obp; j = i - na4; }
  else if (i < na4 + nb4 + nc4) { src = c; dst = oc; j = i - na4 - nb4; }
  else return;
  float4 v = ((const float4*)src)[j];
  ushort4 o;
  o.x = f2bf(v.x); o.y = f2bf(v.y); o.z = f2bf(v.z); o.w = f2bf(v.w);
  ((ushort4*)dst)[j] = o;
}

// ---------------- m97-style GEMM: C[M,N] = A[M,K] * B[N,K]^T + bias ----------------
// MODE 0: scatter bf16 into q/k/v. q,k: [H][4096][64] (q pre-scaled by 8*log2e); v: [H][64][4096].
// MODE 1: fp32 out[M,N] (final projection, N=768)
template <int MODE>
__global__ __launch_bounds__(256, 2) void gemm_bt(
    const u16* __restrict__ A, const u16* __restrict__ B,
    const float* __restrict__ bias,
    u16* __restrict__ qb, u16* __restrict__ kbuf, u16* __restrict__ vb,
    float* __restrict__ outp, int K, int N) {
  __shared__ __align__(16) u16 As[128 * 32];
  __shared__ __align__(16) u16 Bs[128 * 32];
  const int tid = threadIdx.x, lane = tid & 63, w = tid >> 6;
  const int wr = w >> 1, wc = w & 1, quad = lane >> 4, l15 = lane & 15;
  const int m0 = blockIdx.y * 128, n0 = blockIdx.x * 128;

  f32x4 acc[4][4];
#pragma unroll
  for (int i = 0; i < 4; ++i)
#pragma unroll
    for (int j = 0; j < 4; ++j) acc[i][j] = (f32x4){0.f, 0.f, 0.f, 0.f};

  for (int k0 = 0; k0 < K; k0 += 32) {
    __syncthreads();
#pragma unroll
    for (int i = 0; i < 2; ++i) {
      int chunk = i * 256 + w * 64 + lane;     // 512 chunks of 16B per 8KB tile
      int row = chunk >> 2, kc = chunk & 3;
      gload16(A + (size_t)(m0 + row) * K + k0 + kc * 8, (char*)As + chunk * 16);
      gload16(B + (size_t)(n0 + row) * K + k0 + kc * 8, (char*)Bs + chunk * 16);
    }
    __syncthreads();
    bf16x8 af[4], bfr[4];
#pragma unroll
    for (int mi = 0; mi < 4; ++mi)
      af[mi] = *(const bf16x8*)&As[(wr * 64 + mi * 16 + l15) * 32 + quad * 8];
#pragma unroll
    for (int ni = 0; ni < 4; ++ni)
      bfr[ni] = *(const bf16x8*)&Bs[(wc * 64 + ni * 16 + l15) * 32 + quad * 8];
#pragma unroll
    for (int mi = 0; mi < 4; ++mi)
#pragma unroll
      for (int ni = 0; ni < 4; ++ni)
        acc[mi][ni] = __builtin_amdgcn_mfma_f32_16x16x32_bf16(af[mi], bfr[ni], acc[mi][ni], 0, 0, 0);
  }

#pragma unroll
  for (int mi = 0; mi < 4; ++mi) {
    int row = m0 + wr * 64 + mi * 16 + quad * 4;
#pragma unroll
    for (int ni = 0; ni < 4; ++ni) {
      int col = n0 + wc * 64 + ni * 16 + l15;
      float bv = bias[col];
      if (MODE == 0) {
        int t = col / 768;
        int rem = col - t * 768;
        int hh = rem >> 6, d = rem & 63;
        if (t == 2) {  // V: transposed [H][64][4096]; 4 rows pack into one ushort4
          u16* dst = vb + (size_t)hh * 64 * 4096 + (size_t)d * 4096 + row;
          ushort4 pk;
          pk.x = f2bf(acc[mi][ni][0] + bv);
          pk.y = f2bf(acc[mi][ni][1] + bv);
          pk.z = f2bf(acc[mi][ni][2] + bv);
          pk.w = f2bf(acc[mi][ni][3] + bv);
          *(ushort4*)dst = pk;
        } else {
          u16* dst = (t == 0 ? qb : kbuf) + (size_t)hh * 4096 * 64 + d;
          // Q carries sqrt(D)=8 (reference quirk) AND log2(e) so attention does p=exp2(s)
          float sc = (t == 0) ? 11.541560327111707f : 1.f;
#pragma unroll
          for (int r = 0; r < 4; ++r)
            dst[(size_t)(row + r) * 64] = f2bf((acc[mi][ni][r] + bv) * sc);
        }
      } else {
#pragma unroll
        for (int r = 0; r < 4; ++r)
          outp[(size_t)(row + r) * N + col] = acc[mi][ni][r] + bv;
      }
    }
  }
}

// ---------------- flash attention v7: K via LDS (dbuf), V via asm ping-pong prefetch ----------------
// 1 block = (64 q-rows, head); 4 waves x 16-row strips; per-wave P tile in LDS.
// Even iters consume V bank A / load bank B; odd iters the reverse. Loaded bank is first
// read only after the next __syncthreads (vmcnt(0) drain) -> full iteration of latency slack.
__global__ __launch_bounds__(256, 3) void flash_attn(
    const u16* __restrict__ qb, const u16* __restrict__ kb,
    const u16* __restrict__ vtg, u16* __restrict__ ob) {
  constexpr int PLS = 72;  // u16 stride of P rows
  __shared__ __align__(16) u16 Ks[2][64 * 64];   // 8 KB each
  __shared__ __align__(16) u16 pl[4][16 * PLS];  // per-wave P [qrow][key]

  // XCD swizzle: each XCD (b&7) covers 96 consecutive work items = 1.5 heads -> K/V in its L2
  const int b = blockIdx.x;
  const int g = (b & 7) * 96 + (b >> 3);
  const int h = g >> 6;
  const int q0 = (g & 63) * 64;

  const int tid = threadIdx.x, lane = tid & 63, w = tid >> 6;
  const int quad = lane >> 4, l15 = lane & 15;
  const u16* qh = qb + (size_t)h * 4096 * 64;
  const u16* kh = kb + (size_t)h * 4096 * 64;
  // V^T per-lane frag base: row d = dt*16 + l15 (8KB stride), key chunk quad*8 (+32 for hi half)
  const u16* vfp = vtg + (size_t)h * 64 * 4096 + (size_t)l15 * 4096 + quad * 8;
  u16* mypl = &pl[w][0];
  const int sw = l15 & 7;                        // read-side swizzle
  const int u0 = (quad ^ sw) * 8;
  const int u1 = ((quad + 4) ^ sw) * 8;

  // K staging: 512 chunks of 16B per 8KB tile; this thread's 2 chunks
  int c0 = w * 64 + lane, c1 = 256 + w * 64 + lane;
  int r0s = c0 >> 3, j0s = ((c0 & 7) ^ (r0s & 7)) * 8;
  int r1s = c1 >> 3, j1s = ((c1 & 7) ^ (r1s & 7)) * 8;

  // Q B-frags (loop-invariant): n=qrow=q0+w*16+l15, k=d
  bf16x8 qf[2];
#pragma unroll
  for (int c = 0; c < 2; ++c)
    qf[c] = *(const bf16x8*)&qh[(size_t)(q0 + w * 16 + l15) * 64 + c * 32 + quad * 8];

  f32x4 oacc[4];  // O[qrow][d]: C-layout qrow=quad*4+r, d = dt*16 + l15
#pragma unroll
  for (int dt = 0; dt < 4; ++dt) oacc[dt] = (f32x4){0.f, 0.f, 0.f, 0.f};
  float lsum = 0.f;  // per-lane partial (this quad's keys), reduced in epilogue
  const f32x4 zero4 = (f32x4){0.f, 0.f, 0.f, 0.f};

  // V ping-pong register banks (8 frags each = 32 VGPRs/bank)
  bf16x8 va0[4], va1[4], vb0[4], vb1[4];

  // prologue: stage K tile 0 into buffer 0; asm-load V tile 0 into bank A
  gload16(kh + (size_t)r0s * 64 + j0s, (char*)&Ks[0][0] + c0 * 16);
  gload16(kh + (size_t)r1s * 64 + j1s, (char*)&Ks[0][0] + c1 * 16);
#pragma unroll
  for (int dt = 0; dt < 4; ++dt) {
    gld128(va0[dt], vfp + (size_t)dt * 16 * 4096);
    gld128(va1[dt], vfp + (size_t)dt * 16 * 4096 + 32);
  }

  // one attention iteration: consume V bank (vu), prefetch next tile into bank (vl)
  auto body = [&](int t, bf16x8 (&vu0)[4], bf16x8 (&vu1)[4],
                  bf16x8 (&vl0)[4], bf16x8 (&vl1)[4]) {
    const int buf = t & 1;
    __syncthreads();  // K staging of buf complete; V(t) bank landed (vmcnt(0) drain)
    if (t < 63) {     // stage K tile t+1 into buf^1 (drained only at the NEXT barrier)
      int kt1 = (t + 1) * 64;
      gload16(kh + (size_t)(kt1 + r0s) * 64 + j0s, (char*)&Ks[buf ^ 1][0] + c0 * 16);
      gload16(kh + (size_t)(kt1 + r1s) * 64 + j1s, (char*)&Ks[buf ^ 1][0] + c1 * 16);
    }
    // V(t+1) prefetch into the load bank (t=63: harmless dummy reload of tile 63)
    const int tn = (t < 63) ? t + 1 : 63;
    const u16* vt = vfp + (size_t)tn * 64;
#pragma unroll
    for (int dt = 0; dt < 4; ++dt) {
      gld128(vl0[dt], vt + (size_t)dt * 16 * 4096);
      gld128(vl1[dt], vt + (size_t)dt * 16 * 4096 + 32);
    }

    // S^T tiles: A = K from LDS (m=key), B = Q regs (n=qrow); s already in log2 units
    f32x4 st[4];
#pragma unroll
    for (int nt = 0; nt < 4; ++nt) {
      const u16* kp = &Ks[buf][(nt * 16 + l15) * 64];
      bf16x8 kf0 = *(const bf16x8*)(kp + u0);
      bf16x8 kf1 = *(const bf16x8*)(kp + u1);
      f32x4 z = __builtin_amdgcn_mfma_f32_16x16x32_bf16(kf0, qf[0], zero4, 0, 0, 0);
      st[nt] = __builtin_amdgcn_mfma_f32_16x16x32_bf16(kf1, qf[1], z, 0, 0, 0);
    }

    // max-free softmax: p = exp2(s) via raw v_exp_f32; accumulate un-normalized
    float ls = 0.f;
#pragma unroll
    for (int nt = 0; nt < 4; ++nt) {
      float p0 = __builtin_amdgcn_exp2f(st[nt][0]);
      float p1 = __builtin_amdgcn_exp2f(st[nt][1]);
      float p2 = __builtin_amdgcn_exp2f(st[nt][2]);
      float p3 = __builtin_amdgcn_exp2f(st[nt][3]);
      ls += (p0 + p1) + (p2 + p3);
      uint2 pk;
      pk.x = packbf(p0, p1);
      pk.y = packbf(p2, p3);
      // P[qrow=l15][key = nt*16 + quad*4 .. +3]: one 8B write
      *(uint2*)&mypl[l15 * PLS + nt * 16 + quad * 4] = pk;
    }
    lsum += ls;

    // PV: A = P (per-wave LDS round-trip; DS pipe is in-order, no barrier), B = V^T (regs)
    bf16x8 pf0 = *(const bf16x8*)&mypl[l15 * PLS + quad * 8];
    bf16x8 pf1 = *(const bf16x8*)&mypl[l15 * PLS + 32 + quad * 8];
#pragma unroll
    for (int dt = 0; dt < 4; ++dt) {
      oacc[dt] = __builtin_amdgcn_mfma_f32_16x16x32_bf16(pf0, vu0[dt], oacc[dt], 0, 0, 0);
      oacc[dt] = __builtin_amdgcn_mfma_f32_16x16x32_bf16(pf1, vu1[dt], oacc[dt], 0, 0, 0);
    }
  };

  for (int tt = 0; tt < 32; ++tt) {
    body(2 * tt,     va0, va1, vb0, vb1);  // even: use A, load B
    body(2 * tt + 1, vb0, vb1, va0, va1);  // odd:  use B, load A
  }

  // epilogue: reduce lsum across quads (all lanes with same l15 share a qrow)
  lsum += __shfl_xor(lsum, 16);
  lsum += __shfl_xor(lsum, 32);
  float linv = 1.f / lsum;  // per qrow = l15
  float r0 = __shfl(linv, quad * 4 + 0);
  float r1 = __shfl(linv, quad * 4 + 1);
  float r2 = __shfl(linv, quad * 4 + 2);
  float r3 = __shfl(linv, quad * 4 + 3);
#pragma unroll
  for (int dt = 0; dt < 4; ++dt) {
    int d = dt * 16 + l15;
    int row = q0 + w * 16 + quad * 4;
    u16* op = ob + (size_t)row * 768 + h * 64 + d;
    op[0]       = f2bf(oacc[dt][0] * r0);
    op[768]     = f2bf(oacc[dt][1] * r1);
    op[2 * 768] = f2bf(oacc[dt][2] * r2);
    op[3 * 768] = f2bf(oacc[dt][3] * r3);
  }
}

extern "C" void kernel_launch(void* const* d_in, const int* in_sizes, int n_in,
                              void* d_out, int out_size, void* d_ws, size_t ws_size,
                              hipStream_t stream) {
  const float* x      = (const float*)d_in[0];
  const float* qkv_w  = (const float*)d_in[1];
  const float* qkv_b  = (const float*)d_in[2];
  const float* proj_w = (const float*)d_in[3];
  const float* proj_b = (const float*)d_in[4];
  float* out = (float*)d_out;

  const int N = 4096, C = 768, H = 12, D = 64, C3 = 2304;
  char* ws = (char*)d_ws;
  size_t off = 0;
  u16* xb    = (u16*)(ws + off); off += (size_t)N * C * 2;       // 6.29 MB (reused as attn-out)
  u16* wqkv  = (u16*)(ws + off); off += (size_t)C3 * C * 2;      // 3.54 MB
  u16* wproj = (u16*)(ws + off); off += (size_t)C * C * 2;       // 1.18 MB
  u16* qbuf  = (u16*)(ws + off); off += (size_t)H * N * D * 2;   // 6.29 MB
  u16* kbuf  = (u16*)(ws + off); off += (size_t)H * N * D * 2;
  u16* vbuf  = (u16*)(ws + off); off += (size_t)H * N * D * 2;   // V^T [H][64][4096]
  u16* aob = xb;  // alias: xb dead after QKV GEMM

  const int na4 = N * C / 4, nb4 = C3 * C / 4, nc4 = C * C / 4;
  int ntot = na4 + nb4 + nc4;
  cast3<<<(ntot + 255) / 256, 256, 0, stream>>>(x, na4, qkv_w, nb4, proj_w, nc4, xb, wqkv, wproj);

  dim3 g1(C3 / 128, N / 128);  // 18 x 32
  gemm_bt<0><<<g1, 256, 0, stream>>>(xb, wqkv, qkv_b, qbuf, kbuf, vbuf, nullptr, C, C3);

  flash_attn<<<768, 256, 0, stream>>>(qbuf, kbuf, vbuf, aob);

  dim3 g3(C / 128, N / 128);   // 6 x 32
  gemm_bt<1><<<g3, 256, 0, stream>>>(aob, wproj, proj_b, nullptr, nullptr, nullptr, out, C, C);
}

// Round 7
// 138.889 us; speedup vs baseline: 1.8076x; 1.8076x over previous
//
#include <hip/hip_runtime.h>

// Fused attention block for MI355X (gfx950).
// x[4096,768] fp32 -> QKV bf16 GEMM -> flash attention (12 heads, D=64) -> proj GEMM -> fp32 out.
// MFMA v_mfma_f32_16x16x32_bf16 verified layouts:
//   A-frag: m=lane&15, k=quad*8+j ; B-frag: n=lane&15, k=quad*8+j ; C/D: row=quad*4+reg, col=lane&15.
// flash_attn v8 = v4's pipeline (K/V LDS double-buffer + barriers + per-wave P-LDS round trip,
// proven 96.7us) with v2's wave geometry (wave w = (q-half w>>1, key-half w&1), proven correct):
//   each wave reads only its 32-key half of K and V -> K/V frag LDS reads halve.
//   LDS traffic/block-iter: 96 KB -> 60 KB (v4 measured ~95% of the ds-pipe ceiling).
//   v2's mistake (serial permlane P-exchange -> chain-bound) is NOT repeated: P goes through
//   LDS exactly as v4 (decoupled, in-order DS pipe, no barrier, bank-clean pattern).
//   Epilogue: O-partials + lsum combined across key-half waves via dead K/V LDS (v2's code).
// Softmax is UN-NORMALIZED (no running max: logits bounded, exp2 arg << 128); lsum reduced
// once in the epilogue. Q is pre-scaled by 8*log2(e) so p = exp2(s) directly (raw v_exp_f32).
// Lessons encoded: v5 (no prefetch -> latency-bound), v6 (compiler remats V reloads, VGPR=60),
// v7 (ping-pong banks spilled to scratch, VGPR=76) -- V-in-registers abandoned.

typedef short bf16x8 __attribute__((ext_vector_type(8)));
typedef float f32x4 __attribute__((ext_vector_type(4)));
typedef unsigned short u16;
typedef unsigned int u32;

__device__ __forceinline__ u16 f2bf(float f) {
  u32 u = __float_as_uint(f);
  u = (u + 0x7fffu + ((u >> 16) & 1u)) >> 16;  // RNE
  return (u16)u;
}

// pack two fp32 -> bf16 pair (RNE), [a low, b high]; v_perm_b32 grabs both high halves
__device__ __forceinline__ u32 packbf(float a, float b) {
  u32 ua = __float_as_uint(a), ub = __float_as_uint(b);
  ua += 0x7fffu + ((ua >> 16) & 1u);
  ub += 0x7fffu + ((ub >> 16) & 1u);
  return __builtin_amdgcn_perm(ub, ua, 0x07060302);
}

__device__ __forceinline__ void gload16(const void* g, void* l) {
  __builtin_amdgcn_global_load_lds(
      (const __attribute__((address_space(1))) unsigned int*)g,
      (__attribute__((address_space(3))) unsigned int*)l, 16, 0, 0);
}

// ---------------- fused fp32 -> bf16 cast of x, qkv_w, proj_w (one launch) ----------------
__global__ void cast3(const float* __restrict__ a, int na4,
                      const float* __restrict__ b, int nb4,
                      const float* __restrict__ c, int nc4,
                      u16* __restrict__ oa, u16* __restrict__ obp, u16* __restrict__ oc) {
  int i = blockIdx.x * blockDim.x + threadIdx.x;
  const float* src;
  u16* dst;
  int j = i;
  if (i < na4) { src = a; dst = oa; }
  else if (i < na4 + nb4) { src = b; dst = obp; j = i - na4; }
  else if (i < na4 + nb4 + nc4) { src = c; dst = oc; j = i - na4 - nb4; }
  else return;
  float4 v = ((const float4*)src)[j];
  ushort4 o;
  o.x = f2bf(v.x); o.y = f2bf(v.y); o.z = f2bf(v.z); o.w = f2bf(v.w);
  ((ushort4*)dst)[j] = o;
}

// ---------------- m97-style GEMM: C[M,N] = A[M,K] * B[N,K]^T + bias ----------------
// MODE 0: scatter bf16 into q/k/v. q,k: [H][4096][64] (q pre-scaled by 8*log2e); v: [H][64][4096].
// MODE 1: fp32 out[M,N] (final projection, N=768)
template <int MODE>
__global__ __launch_bounds__(256, 2) void gemm_bt(
    const u16* __restrict__ A, const u16* __restrict__ B,
    const float* __restrict__ bias,
    u16* __restrict__ qb, u16* __restrict__ kbuf, u16* __restrict__ vb,
    float* __restrict__ outp, int K, int N) {
  __shared__ __align__(16) u16 As[128 * 32];
  __shared__ __align__(16) u16 Bs[128 * 32];
  const int tid = threadIdx.x, lane = tid & 63, w = tid >> 6;
  const int wr = w >> 1, wc = w & 1, quad = lane >> 4, l15 = lane & 15;
  const int m0 = blockIdx.y * 128, n0 = blockIdx.x * 128;

  f32x4 acc[4][4];
#pragma unroll
  for (int i = 0; i < 4; ++i)
#pragma unroll
    for (int j = 0; j < 4; ++j) acc[i][j] = (f32x4){0.f, 0.f, 0.f, 0.f};

  for (int k0 = 0; k0 < K; k0 += 32) {
    __syncthreads();
#pragma unroll
    for (int i = 0; i < 2; ++i) {
      int chunk = i * 256 + w * 64 + lane;     // 512 chunks of 16B per 8KB tile
      int row = chunk >> 2, kc = chunk & 3;
      gload16(A + (size_t)(m0 + row) * K + k0 + kc * 8, (char*)As + chunk * 16);
      gload16(B + (size_t)(n0 + row) * K + k0 + kc * 8, (char*)Bs + chunk * 16);
    }
    __syncthreads();
    bf16x8 af[4], bfr[4];
#pragma unroll
    for (int mi = 0; mi < 4; ++mi)
      af[mi] = *(const bf16x8*)&As[(wr * 64 + mi * 16 + l15) * 32 + quad * 8];
#pragma unroll
    for (int ni = 0; ni < 4; ++ni)
      bfr[ni] = *(const bf16x8*)&Bs[(wc * 64 + ni * 16 + l15) * 32 + quad * 8];
#pragma unroll
    for (int mi = 0; mi < 4; ++mi)
#pragma unroll
      for (int ni = 0; ni < 4; ++ni)
        acc[mi][ni] = __builtin_amdgcn_mfma_f32_16x16x32_bf16(af[mi], bfr[ni], acc[mi][ni], 0, 0, 0);
  }

#pragma unroll
  for (int mi = 0; mi < 4; ++mi) {
    int row = m0 + wr * 64 + mi * 16 + quad * 4;
#pragma unroll
    for (int ni = 0; ni < 4; ++ni) {
      int col = n0 + wc * 64 + ni * 16 + l15;
      float bv = bias[col];
      if (MODE == 0) {
        int t = col / 768;
        int rem = col - t * 768;
        int hh = rem >> 6, d = rem & 63;
        if (t == 2) {  // V: transposed [H][64][4096]; 4 rows pack into one ushort4
          u16* dst = vb + (size_t)hh * 64 * 4096 + (size_t)d * 4096 + row;
          ushort4 pk;
          pk.x = f2bf(acc[mi][ni][0] + bv);
          pk.y = f2bf(acc[mi][ni][1] + bv);
          pk.z = f2bf(acc[mi][ni][2] + bv);
          pk.w = f2bf(acc[mi][ni][3] + bv);
          *(ushort4*)dst = pk;
        } else {
          u16* dst = (t == 0 ? qb : kbuf) + (size_t)hh * 4096 * 64 + d;
          // Q carries sqrt(D)=8 (reference quirk) AND log2(e) so attention does p=exp2(s)
          float sc = (t == 0) ? 11.541560327111707f : 1.f;
#pragma unroll
          for (int r = 0; r < 4; ++r)
            dst[(size_t)(row + r) * 64] = f2bf((acc[mi][ni][r] + bv) * sc);
        }
      } else {
#pragma unroll
        for (int r = 0; r < 4; ++r)
          outp[(size_t)(row + r) * N + col] = acc[mi][ni][r] + bv;
      }
    }
  }
}

// ---------------- flash attention v8: 32q x 32k wave split, K/V LDS dbuf, P via LDS ----------------
// 1 block = (64 q-rows, head). 4 waves: wave w = (q-half w>>1 [32 qrows], key-half w&1 [32 keys]).
// Per wave-iter: 4 K-frag + 4 V-frag ds_read_b128 (half of v4), 8 S-MFMA, exp2 softmax,
// P LDS round-trip (v4 pattern), 8 PV-MFMA. Epilogue combines key-half partials via dead LDS.
__global__ __launch_bounds__(256, 3) void flash_attn(
    const u16* __restrict__ qb, const u16* __restrict__ kb,
    const u16* __restrict__ vtg, u16* __restrict__ ob) {
  constexpr int PLS = 72;  // u16 stride of P rows (same bank-clean pattern as v4)
  __shared__ __align__(16) u16 Ks[2][64 * 64];   // 8 KB each
  __shared__ __align__(16) u16 Vs[2][64 * 64];
  __shared__ __align__(16) u16 pl[4][16 * PLS];  // per-wave P [qrow 16][key 64(2 qt x 32)]

  // XCD swizzle: each XCD (b&7) covers 96 consecutive work items = 1.5 heads -> K/V in its L2
  const int b = blockIdx.x;
  const int g = (b & 7) * 96 + (b >> 3);
  const int h = g >> 6;
  const int q0 = (g & 63) * 64;

  const int tid = threadIdx.x, lane = tid & 63, w = tid >> 6;
  const int quad = lane >> 4, l15 = lane & 15;
  const int qh2 = w >> 1, kh = w & 1;            // wave role: (q-half, key-half)
  const u16* qptr = qb + (size_t)h * 4096 * 64;
  const u16* kptr = kb + (size_t)h * 4096 * 64;
  const u16* vptr = vtg + (size_t)h * 64 * 4096; // [d][key]
  u16* mypl = &pl[w][0];
  const int sw = l15 & 7;                        // read-side swizzle (row&7 == l15&7 for all reads)
  const int u0 = (quad ^ sw) * 8;                // K d-chunk c=0
  const int u1 = ((quad + 4) ^ sw) * 8;          // K d-chunk c=1
  const int uv = (((kh << 2) + quad) ^ sw) * 8;  // V key-chunk for this wave's key-half

  // staging: 512 chunks of 16B per tile; this thread's 2 chunks per tile
  int c0 = w * 64 + lane, c1 = 256 + w * 64 + lane;
  int r0s = c0 >> 3, j0s = ((c0 & 7) ^ (r0s & 7)) * 8;
  int r1s = c1 >> 3, j1s = ((c1 & 7) ^ (r1s & 7)) * 8;

  // Q B-frags (loop-invariant): n=qrow = q0 + qh2*32 + qt*16 + l15, k=d
  bf16x8 qf[2][2];
#pragma unroll
  for (int qt = 0; qt < 2; ++qt)
#pragma unroll
    for (int c = 0; c < 2; ++c)
      qf[qt][c] = *(const bf16x8*)&qptr[(size_t)(q0 + qh2 * 32 + qt * 16 + l15) * 64 + c * 32 + quad * 8];

  f32x4 oacc[2][4];  // O-partial[qt][dt]: row=quad*4+r (qrow), col=l15 (d); this wave's key-half only
#pragma unroll
  for (int qt = 0; qt < 2; ++qt)
#pragma unroll
    for (int dt = 0; dt < 4; ++dt) oacc[qt][dt] = (f32x4){0.f, 0.f, 0.f, 0.f};
  float lsum[2] = {0.f, 0.f};  // per-lane partial exp-sums, one per q-tile
  const f32x4 zero4 = (f32x4){0.f, 0.f, 0.f, 0.f};

  // prologue: stage tile 0 into buffer 0
  gload16(kptr + (size_t)r0s * 64 + j0s, (char*)&Ks[0][0] + c0 * 16);
  gload16(kptr + (size_t)r1s * 64 + j1s, (char*)&Ks[0][0] + c1 * 16);
  gload16(vptr + (size_t)r0s * 4096 + j0s, (char*)&Vs[0][0] + c0 * 16);
  gload16(vptr + (size_t)r1s * 4096 + j1s, (char*)&Vs[0][0] + c1 * 16);

  for (int t = 0; t < 64; ++t) {
    const int buf = t & 1;
    __syncthreads();  // staging of buf complete; all waves done computing on buf^1
    if (t < 63) {     // stage tile t+1 into buf^1 (drained only at the NEXT barrier)
      int kt1 = (t + 1) * 64;
      gload16(kptr + (size_t)(kt1 + r0s) * 64 + j0s, (char*)&Ks[buf ^ 1][0] + c0 * 16);
      gload16(kptr + (size_t)(kt1 + r1s) * 64 + j1s, (char*)&Ks[buf ^ 1][0] + c1 * 16);
      gload16(vptr + (size_t)r0s * 4096 + kt1 + j0s, (char*)&Vs[buf ^ 1][0] + c0 * 16);
      gload16(vptr + (size_t)r1s * 4096 + kt1 + j1s, (char*)&Vs[buf ^ 1][0] + c1 * 16);
    }

    // K A-frags for this wave's 32-key half: m=key = kh*32 + mt*16 + l15 (row&7 == l15&7)
    bf16x8 kf[2][2];
#pragma unroll
    for (int mt = 0; mt < 2; ++mt) {
      const u16* kr = &Ks[buf][((kh << 5) + mt * 16 + l15) * 64];
      kf[mt][0] = *(const bf16x8*)(kr + u0);
      kf[mt][1] = *(const bf16x8*)(kr + u1);
    }
    // S^T tiles: A = K (m=key), B = Q regs (n=qrow); s already in log2 units
    // Lane holds S[key = kh*32 + mt*16 + quad*4 + r][qrow = qt*16 + l15]
    f32x4 st[2][2];  // [mt][qt]
#pragma unroll
    for (int mt = 0; mt < 2; ++mt)
#pragma unroll
      for (int qt = 0; qt < 2; ++qt) {
        f32x4 z = __builtin_amdgcn_mfma_f32_16x16x32_bf16(kf[mt][0], qf[qt][0], zero4, 0, 0, 0);
        st[mt][qt] = __builtin_amdgcn_mfma_f32_16x16x32_bf16(kf[mt][1], qf[qt][1], z, 0, 0, 0);
      }

    // V^T B-frags (this key-half; LGKM overlaps the exp VALU below): n=d, k=local key 0..31
    bf16x8 vf[4];
#pragma unroll
    for (int dt = 0; dt < 4; ++dt)
      vf[dt] = *(const bf16x8*)(&Vs[buf][(dt * 16 + l15) * 64] + uv);

    // max-free softmax: p = exp2(s) via raw v_exp_f32; accumulate un-normalized.
    // P[qrow=l15][qt*32 + mt*16 + quad*4 .. +3] <- one 8B write per (qt,mt) (v4 pattern).
#pragma unroll
    for (int qt = 0; qt < 2; ++qt) {
      float ls = 0.f;
#pragma unroll
      for (int mt = 0; mt < 2; ++mt) {
        float p0 = __builtin_amdgcn_exp2f(st[mt][qt][0]);
        float p1 = __builtin_amdgcn_exp2f(st[mt][qt][1]);
        float p2 = __builtin_amdgcn_exp2f(st[mt][qt][2]);
        float p3 = __builtin_amdgcn_exp2f(st[mt][qt][3]);
        ls += (p0 + p1) + (p2 + p3);
        uint2 pk;
        pk.x = packbf(p0, p1);
        pk.y = packbf(p2, p3);
        *(uint2*)&mypl[l15 * PLS + qt * 32 + mt * 16 + quad * 4] = pk;
      }
      lsum[qt] += ls;
    }

    // PV: A = P (per-wave LDS round-trip; DS pipe is in-order, no barrier), B = V^T.
    // One MFMA per (qt,dt): k=quad*8+j covers this wave's full 32-key half.
    bf16x8 pf[2];
#pragma unroll
    for (int qt = 0; qt < 2; ++qt)
      pf[qt] = *(const bf16x8*)&mypl[l15 * PLS + qt * 32 + quad * 8];
#pragma unroll
    for (int qt = 0; qt < 2; ++qt)
#pragma unroll
      for (int dt = 0; dt < 4; ++dt)
        oacc[qt][dt] = __builtin_amdgcn_mfma_f32_16x16x32_bf16(pf[qt], vf[dt], oacc[qt][dt], 0, 0, 0);
  }

  // ---- epilogue: reduce across quads, then across key-half waves via dead K/V LDS ----
  __syncthreads();  // all waves done reading Ks/Vs; safe to reuse as reduction scratch
#pragma unroll
  for (int qt = 0; qt < 2; ++qt) {
    lsum[qt] += __shfl_xor(lsum[qt], 16);
    lsum[qt] += __shfl_xor(lsum[qt], 32);  // now per-qrow(l15) sum over this wave's 32 keys
  }
  float* ored = (float*)&Ks[0][0];  // 2qh x 2qt x 4dt x 64lane x f32x4 = 16 KB (= both Ks bufs)
  float* lred = (float*)&Vs[0][0];  // 2qh x 2qt x 16 floats
  if (kh == 1) {
#pragma unroll
    for (int qt = 0; qt < 2; ++qt) {
#pragma unroll
      for (int dt = 0; dt < 4; ++dt)
        *(f32x4*)&ored[((((qh2 * 2 + qt) * 4 + dt) * 64) + lane) * 4] = oacc[qt][dt];
      if (quad == 0) lred[(qh2 * 2 + qt) * 16 + l15] = lsum[qt];
    }
  }
  __syncthreads();
  if (kh == 0) {
#pragma unroll
    for (int qt = 0; qt < 2; ++qt) {
      float linv = 1.f / (lsum[qt] + lred[(qh2 * 2 + qt) * 16 + l15]);  // per qrow = l15
      float r0 = __shfl(linv, quad * 4 + 0);
      float r1 = __shfl(linv, quad * 4 + 1);
      float r2 = __shfl(linv, quad * 4 + 2);
      float r3 = __shfl(linv, quad * 4 + 3);
#pragma unroll
      for (int dt = 0; dt < 4; ++dt) {
        f32x4 oo = *(const f32x4*)&ored[((((qh2 * 2 + qt) * 4 + dt) * 64) + lane) * 4];
        int row = q0 + qh2 * 32 + qt * 16 + quad * 4;
        u16* op = ob + (size_t)row * 768 + h * 64 + dt * 16 + l15;
        op[0]       = f2bf((oacc[qt][dt][0] + oo[0]) * r0);
        op[768]     = f2bf((oacc[qt][dt][1] + oo[1]) * r1);
        op[2 * 768] = f2bf((oacc[qt][dt][2] + oo[2]) * r2);
        op[3 * 768] = f2bf((oacc[qt][dt][3] + oo[3]) * r3);
      }
    }
  }
}

extern "C" void kernel_launch(void* const* d_in, const int* in_sizes, int n_in,
                              void* d_out, int out_size, void* d_ws, size_t ws_size,
                              hipStream_t stream) {
  const float* x      = (const float*)d_in[0];
  const float* qkv_w  = (const float*)d_in[1];
  const float* qkv_b  = (const float*)d_in[2];
  const float* proj_w = (const float*)d_in[3];
  const float* proj_b = (const float*)d_in[4];
  float* out = (float*)d_out;

  const int N = 4096, C = 768, H = 12, D = 64, C3 = 2304;
  char* ws = (char*)d_ws;
  size_t off = 0;
  u16* xb    = (u16*)(ws + off); off += (size_t)N * C * 2;       // 6.29 MB (reused as attn-out)
  u16* wqkv  = (u16*)(ws + off); off += (size_t)C3 * C * 2;      // 3.54 MB
  u16* wproj = (u16*)(ws + off); off += (size_t)C * C * 2;       // 1.18 MB
  u16* qbuf  = (u16*)(ws + off); off += (size_t)H * N * D * 2;   // 6.29 MB
  u16* kbuf  = (u16*)(ws + off); off += (size_t)H * N * D * 2;
  u16* vbuf  = (u16*)(ws + off); off += (size_t)H * N * D * 2;   // V^T [H][64][4096]
  u16* aob = xb;  // alias: xb dead after QKV GEMM

  const int na4 = N * C / 4, nb4 = C3 * C / 4, nc4 = C * C / 4;
  int ntot = na4 + nb4 + nc4;
  cast3<<<(ntot + 255) / 256, 256, 0, stream>>>(x, na4, qkv_w, nb4, proj_w, nc4, xb, wqkv, wproj);

  dim3 g1(C3 / 128, N / 128);  // 18 x 32
  gemm_bt<0><<<g1, 256, 0, stream>>>(xb, wqkv, qkv_b, qbuf, kbuf, vbuf, nullptr, C, C3);

  flash_attn<<<768, 256, 0, stream>>>(qbuf, kbuf, vbuf, aob);

  dim3 g3(C / 128, N / 128);   // 6 x 32
  gemm_bt<1><<<g3, 256, 0, stream>>>(aob, wproj, proj_b, nullptr, nullptr, nullptr, out, C, C);
}

// Round 8
// 132.911 us; speedup vs baseline: 1.8889x; 1.0450x over previous
//
#include <hip/hip_runtime.h>

// Fused attention block for MI355X (gfx950).
// x[4096,768] fp32 -> QKV bf16 GEMM -> flash attention (12 heads, D=64) -> proj GEMM -> fp32 out.
// MFMA v_mfma_f32_16x16x32_bf16 verified layouts:
//   A-frag: m=lane&15, k=quad*8+j ; B-frag: n=lane&15, k=quad*8+j ; C/D: row=quad*4+reg, col=lane&15.
// flash_attn v9 = v8 (32q x 32k wave split + K/V LDS dbuf + P-LDS round trip, proven 92.7us)
//   + deferred-PV software pipeline: P(t)/V(t) frags held in regs across the barrier; PV(t-1)
//     issues at the top of iter t under the K ds_read latency (8 pure-register MFMAs).
//     Removes PV + P-read-wait from the per-iter serial chain; P-read latency hidden by the
//     barrier's lgkm drain.
//   + P packed via v_cvt_pk_bf16_f32 (1 op/pair vs 7-op hand-RNE; same RNE numerics) --
//     VALUBusy was 48%, the largest pipe; pack was ~17% of per-wave VALU.
// Softmax is UN-NORMALIZED (no running max: logits bounded, exp2 arg << 128); lsum reduced
// once in the epilogue. Q is pre-scaled by 8*log2(e) so p = exp2(s) directly (raw v_exp_f32).
// Lessons encoded: v5 (no prefetch -> latency-bound), v6 (compiler remats V reloads), v7 (reg
// banks spilled), v8 (LDS-BW relieved; VALU+chain became binding).

typedef short bf16x8 __attribute__((ext_vector_type(8)));
typedef float f32x4 __attribute__((ext_vector_type(4)));
typedef unsigned short u16;
typedef unsigned int u32;

__device__ __forceinline__ u16 f2bf(float f) {
  u32 u = __float_as_uint(f);
  u = (u + 0x7fffu + ((u >> 16) & 1u)) >> 16;  // RNE
  return (u16)u;
}

// HW packed f32x2 -> bf16x2 (RNE; the standard fptrunc lowering on gfx950): [a low, b high]
__device__ __forceinline__ u32 cvtpk(float a, float b) {
  u32 r;
  asm("v_cvt_pk_bf16_f32 %0, %1, %2" : "=v"(r) : "v"(a), "v"(b));
  return r;
}

__device__ __forceinline__ void gload16(const void* g, void* l) {
  __builtin_amdgcn_global_load_lds(
      (const __attribute__((address_space(1))) unsigned int*)g,
      (__attribute__((address_space(3))) unsigned int*)l, 16, 0, 0);
}

// ---------------- fused fp32 -> bf16 cast of x, qkv_w, proj_w (one launch) ----------------
__global__ void cast3(const float* __restrict__ a, int na4,
                      const float* __restrict__ b, int nb4,
                      const float* __restrict__ c, int nc4,
                      u16* __restrict__ oa, u16* __restrict__ obp, u16* __restrict__ oc) {
  int i = blockIdx.x * blockDim.x + threadIdx.x;
  const float* src;
  u16* dst;
  int j = i;
  if (i < na4) { src = a; dst = oa; }
  else if (i < na4 + nb4) { src = b; dst = obp; j = i - na4; }
  else if (i < na4 + nb4 + nc4) { src = c; dst = oc; j = i - na4 - nb4; }
  else return;
  float4 v = ((const float4*)src)[j];
  ushort4 o;
  o.x = f2bf(v.x); o.y = f2bf(v.y); o.z = f2bf(v.z); o.w = f2bf(v.w);
  ((ushort4*)dst)[j] = o;
}

// ---------------- m97-style GEMM: C[M,N] = A[M,K] * B[N,K]^T + bias ----------------
// MODE 0: scatter bf16 into q/k/v. q,k: [H][4096][64] (q pre-scaled by 8*log2e); v: [H][64][4096].
// MODE 1: fp32 out[M,N] (final projection, N=768)
template <int MODE>
__global__ __launch_bounds__(256, 2) void gemm_bt(
    const u16* __restrict__ A, const u16* __restrict__ B,
    const float* __restrict__ bias,
    u16* __restrict__ qb, u16* __restrict__ kbuf, u16* __restrict__ vb,
    float* __restrict__ outp, int K, int N) {
  __shared__ __align__(16) u16 As[128 * 32];
  __shared__ __align__(16) u16 Bs[128 * 32];
  const int tid = threadIdx.x, lane = tid & 63, w = tid >> 6;
  const int wr = w >> 1, wc = w & 1, quad = lane >> 4, l15 = lane & 15;
  const int m0 = blockIdx.y * 128, n0 = blockIdx.x * 128;

  f32x4 acc[4][4];
#pragma unroll
  for (int i = 0; i < 4; ++i)
#pragma unroll
    for (int j = 0; j < 4; ++j) acc[i][j] = (f32x4){0.f, 0.f, 0.f, 0.f};

  for (int k0 = 0; k0 < K; k0 += 32) {
    __syncthreads();
#pragma unroll
    for (int i = 0; i < 2; ++i) {
      int chunk = i * 256 + w * 64 + lane;     // 512 chunks of 16B per 8KB tile
      int row = chunk >> 2, kc = chunk & 3;
      gload16(A + (size_t)(m0 + row) * K + k0 + kc * 8, (char*)As + chunk * 16);
      gload16(B + (size_t)(n0 + row) * K + k0 + kc * 8, (char*)Bs + chunk * 16);
    }
    __syncthreads();
    bf16x8 af[4], bfr[4];
#pragma unroll
    for (int mi = 0; mi < 4; ++mi)
      af[mi] = *(const bf16x8*)&As[(wr * 64 + mi * 16 + l15) * 32 + quad * 8];
#pragma unroll
    for (int ni = 0; ni < 4; ++ni)
      bfr[ni] = *(const bf16x8*)&Bs[(wc * 64 + ni * 16 + l15) * 32 + quad * 8];
#pragma unroll
    for (int mi = 0; mi < 4; ++mi)
#pragma unroll
      for (int ni = 0; ni < 4; ++ni)
        acc[mi][ni] = __builtin_amdgcn_mfma_f32_16x16x32_bf16(af[mi], bfr[ni], acc[mi][ni], 0, 0, 0);
  }

#pragma unroll
  for (int mi = 0; mi < 4; ++mi) {
    int row = m0 + wr * 64 + mi * 16 + quad * 4;
#pragma unroll
    for (int ni = 0; ni < 4; ++ni) {
      int col = n0 + wc * 64 + ni * 16 + l15;
      float bv = bias[col];
      if (MODE == 0) {
        int t = col / 768;
        int rem = col - t * 768;
        int hh = rem >> 6, d = rem & 63;
        if (t == 2) {  // V: transposed [H][64][4096]; 4 rows pack into one ushort4
          u16* dst = vb + (size_t)hh * 64 * 4096 + (size_t)d * 4096 + row;
          ushort4 pk;
          pk.x = f2bf(acc[mi][ni][0] + bv);
          pk.y = f2bf(acc[mi][ni][1] + bv);
          pk.z = f2bf(acc[mi][ni][2] + bv);
          pk.w = f2bf(acc[mi][ni][3] + bv);
          *(ushort4*)dst = pk;
        } else {
          u16* dst = (t == 0 ? qb : kbuf) + (size_t)hh * 4096 * 64 + d;
          // Q carries sqrt(D)=8 (reference quirk) AND log2(e) so attention does p=exp2(s)
          float sc = (t == 0) ? 11.541560327111707f : 1.f;
#pragma unroll
          for (int r = 0; r < 4; ++r)
            dst[(size_t)(row + r) * 64] = f2bf((acc[mi][ni][r] + bv) * sc);
        }
      } else {
#pragma unroll
        for (int r = 0; r < 4; ++r)
          outp[(size_t)(row + r) * N + col] = acc[mi][ni][r] + bv;
      }
    }
  }
}

// ---------------- flash attention v9: wave split + deferred-PV pipeline ----------------
// 1 block = (64 q-rows, head). 4 waves: wave w = (q-half w>>1 [32 qrows], key-half w&1 [32 keys]).
// Iter t: barrier; stage t+1; issue K(t) ds_reads; PV(t-1) (pure-reg MFMAs under K latency);
// S(t); V(t)->regs; softmax(t) (exp2 + cvt_pk); P(t) write+read -> regs. PV(63) after the loop.
__global__ __launch_bounds__(256, 3) void flash_attn(
    const u16* __restrict__ qb, const u16* __restrict__ kb,
    const u16* __restrict__ vtg, u16* __restrict__ ob) {
  constexpr int PLS = 72;  // u16 stride of P rows (same bank-clean pattern as v4/v8)
  __shared__ __align__(16) u16 Ks[2][64 * 64];   // 8 KB each
  __shared__ __align__(16) u16 Vs[2][64 * 64];
  __shared__ __align__(16) u16 pl[4][16 * PLS];  // per-wave P [qrow 16][key 64(2 qt x 32)]

  // XCD swizzle: each XCD (b&7) covers 96 consecutive work items = 1.5 heads -> K/V in its L2
  const int b = blockIdx.x;
  const int g = (b & 7) * 96 + (b >> 3);
  const int h = g >> 6;
  const int q0 = (g & 63) * 64;

  const int tid = threadIdx.x, lane = tid & 63, w = tid >> 6;
  const int quad = lane >> 4, l15 = lane & 15;
  const int qh2 = w >> 1, kh = w & 1;            // wave role: (q-half, key-half)
  const u16* qptr = qb + (size_t)h * 4096 * 64;
  const u16* kptr = kb + (size_t)h * 4096 * 64;
  const u16* vptr = vtg + (size_t)h * 64 * 4096; // [d][key]
  u16* mypl = &pl[w][0];
  const int sw = l15 & 7;                        // read-side swizzle (row&7 == l15&7 for all reads)
  const int u0 = (quad ^ sw) * 8;                // K d-chunk c=0
  const int u1 = ((quad + 4) ^ sw) * 8;          // K d-chunk c=1
  const int uv = (((kh << 2) + quad) ^ sw) * 8;  // V key-chunk for this wave's key-half

  // staging: 512 chunks of 16B per tile; this thread's 2 chunks per tile
  int c0 = w * 64 + lane, c1 = 256 + w * 64 + lane;
  int r0s = c0 >> 3, j0s = ((c0 & 7) ^ (r0s & 7)) * 8;
  int r1s = c1 >> 3, j1s = ((c1 & 7) ^ (r1s & 7)) * 8;

  // Q B-frags (loop-invariant): n=qrow = q0 + qh2*32 + qt*16 + l15, k=d
  bf16x8 qf[2][2];
#pragma unroll
  for (int qt = 0; qt < 2; ++qt)
#pragma unroll
    for (int c = 0; c < 2; ++c)
      qf[qt][c] = *(const bf16x8*)&qptr[(size_t)(q0 + qh2 * 32 + qt * 16 + l15) * 64 + c * 32 + quad * 8];

  f32x4 oacc[2][4];  // O-partial[qt][dt]: row=quad*4+r (qrow), col=l15 (d); this wave's key-half only
#pragma unroll
  for (int qt = 0; qt < 2; ++qt)
#pragma unroll
    for (int dt = 0; dt < 4; ++dt) oacc[qt][dt] = (f32x4){0.f, 0.f, 0.f, 0.f};
  float lsum[2] = {0.f, 0.f};  // per-lane partial exp-sums, one per q-tile
  const f32x4 zero4 = (f32x4){0.f, 0.f, 0.f, 0.f};

  // pipeline registers: P(t) and V(t) frags carried to iteration t+1
  bf16x8 pfprev[2], vprev[4];

  // prologue: stage tile 0 into buffer 0
  gload16(kptr + (size_t)r0s * 64 + j0s, (char*)&Ks[0][0] + c0 * 16);
  gload16(kptr + (size_t)r1s * 64 + j1s, (char*)&Ks[0][0] + c1 * 16);
  gload16(vptr + (size_t)r0s * 4096 + j0s, (char*)&Vs[0][0] + c0 * 16);
  gload16(vptr + (size_t)r1s * 4096 + j1s, (char*)&Vs[0][0] + c1 * 16);

  for (int t = 0; t < 64; ++t) {
    const int buf = t & 1;
    __syncthreads();  // staging of buf complete; P(t-1)/V(t-1) reg reads drained (lgkm 0)
    if (t < 63) {     // stage tile t+1 into buf^1 (drained only at the NEXT barrier)
      int kt1 = (t + 1) * 64;
      gload16(kptr + (size_t)(kt1 + r0s) * 64 + j0s, (char*)&Ks[buf ^ 1][0] + c0 * 16);
      gload16(kptr + (size_t)(kt1 + r1s) * 64 + j1s, (char*)&Ks[buf ^ 1][0] + c1 * 16);
      gload16(vptr + (size_t)r0s * 4096 + kt1 + j0s, (char*)&Vs[buf ^ 1][0] + c0 * 16);
      gload16(vptr + (size_t)r1s * 4096 + kt1 + j1s, (char*)&Vs[buf ^ 1][0] + c1 * 16);
    }

    // K A-frags for this wave's 32-key half: m=key = kh*32 + mt*16 + l15 (issue first)
    bf16x8 kf[2][2];
#pragma unroll
    for (int mt = 0; mt < 2; ++mt) {
      const u16* kr = &Ks[buf][((kh << 5) + mt * 16 + l15) * 64];
      kf[mt][0] = *(const bf16x8*)(kr + u0);
      kf[mt][1] = *(const bf16x8*)(kr + u1);
    }

    // PV(t-1): pure-register MFMAs — execute under the K ds_read latency
    if (t > 0) {
#pragma unroll
      for (int qt = 0; qt < 2; ++qt)
#pragma unroll
        for (int dt = 0; dt < 4; ++dt)
          oacc[qt][dt] = __builtin_amdgcn_mfma_f32_16x16x32_bf16(pfprev[qt], vprev[dt], oacc[qt][dt], 0, 0, 0);
    }

    // S^T tiles: A = K (m=key), B = Q regs (n=qrow); s already in log2 units
    // Lane holds S[key = kh*32 + mt*16 + quad*4 + r][qrow = qt*16 + l15]
    f32x4 st[2][2];  // [mt][qt]
#pragma unroll
    for (int mt = 0; mt < 2; ++mt)
#pragma unroll
      for (int qt = 0; qt < 2; ++qt) {
        f32x4 z = __builtin_amdgcn_mfma_f32_16x16x32_bf16(kf[mt][0], qf[qt][0], zero4, 0, 0, 0);
        st[mt][qt] = __builtin_amdgcn_mfma_f32_16x16x32_bf16(kf[mt][1], qf[qt][1], z, 0, 0, 0);
      }

    // V^T B-frags (this key-half) -> carried regs; LGKM overlaps the exp VALU below
#pragma unroll
    for (int dt = 0; dt < 4; ++dt)
      vprev[dt] = *(const bf16x8*)(&Vs[buf][(dt * 16 + l15) * 64] + uv);

    // max-free softmax: p = exp2(s) via raw v_exp_f32; pack via v_cvt_pk_bf16_f32.
    // P[qrow=l15][qt*32 + mt*16 + quad*4 .. +3] <- one 8B write per (qt,mt).
#pragma unroll
    for (int qt = 0; qt < 2; ++qt) {
      float ls = 0.f;
#pragma unroll
      for (int mt = 0; mt < 2; ++mt) {
        float p0 = __builtin_amdgcn_exp2f(st[mt][qt][0]);
        float p1 = __builtin_amdgcn_exp2f(st[mt][qt][1]);
        float p2 = __builtin_amdgcn_exp2f(st[mt][qt][2]);
        float p3 = __builtin_amdgcn_exp2f(st[mt][qt][3]);
        ls += (p0 + p1) + (p2 + p3);
        uint2 pk;
        pk.x = cvtpk(p0, p1);
        pk.y = cvtpk(p2, p3);
        *(uint2*)&mypl[l15 * PLS + qt * 32 + mt * 16 + quad * 4] = pk;
      }
      lsum[qt] += ls;
    }

    // P(t) read-back into carried regs (in-order DS pipe; latency hidden by next barrier)
#pragma unroll
    for (int qt = 0; qt < 2; ++qt)
      pfprev[qt] = *(const bf16x8*)&mypl[l15 * PLS + qt * 32 + quad * 8];
  }

  // drain the pipeline: PV(63)
#pragma unroll
  for (int qt = 0; qt < 2; ++qt)
#pragma unroll
    for (int dt = 0; dt < 4; ++dt)
      oacc[qt][dt] = __builtin_amdgcn_mfma_f32_16x16x32_bf16(pfprev[qt], vprev[dt], oacc[qt][dt], 0, 0, 0);

  // ---- epilogue: reduce across quads, then across key-half waves via dead K/V LDS ----
  __syncthreads();  // all waves done reading Ks/Vs; safe to reuse as reduction scratch
#pragma unroll
  for (int qt = 0; qt < 2; ++qt) {
    lsum[qt] += __shfl_xor(lsum[qt], 16);
    lsum[qt] += __shfl_xor(lsum[qt], 32);  // now per-qrow(l15) sum over this wave's 32 keys
  }
  float* ored = (float*)&Ks[0][0];  // 2qh x 2qt x 4dt x 64lane x f32x4 = 16 KB (= both Ks bufs)
  float* lred = (float*)&Vs[0][0];  // 2qh x 2qt x 16 floats
  if (kh == 1) {
#pragma unroll
    for (int qt = 0; qt < 2; ++qt) {
#pragma unroll
      for (int dt = 0; dt < 4; ++dt)
        *(f32x4*)&ored[((((qh2 * 2 + qt) * 4 + dt) * 64) + lane) * 4] = oacc[qt][dt];
      if (quad == 0) lred[(qh2 * 2 + qt) * 16 + l15] = lsum[qt];
    }
  }
  __syncthreads();
  if (kh == 0) {
#pragma unroll
    for (int qt = 0; qt < 2; ++qt) {
      float linv = 1.f / (lsum[qt] + lred[(qh2 * 2 + qt) * 16 + l15]);  // per qrow = l15
      float r0 = __shfl(linv, quad * 4 + 0);
      float r1 = __shfl(linv, quad * 4 + 1);
      float r2 = __shfl(linv, quad * 4 + 2);
      float r3 = __shfl(linv, quad * 4 + 3);
#pragma unroll
      for (int dt = 0; dt < 4; ++dt) {
        f32x4 oo = *(const f32x4*)&ored[((((qh2 * 2 + qt) * 4 + dt) * 64) + lane) * 4];
        int row = q0 + qh2 * 32 + qt * 16 + quad * 4;
        u16* op = ob + (size_t)row * 768 + h * 64 + dt * 16 + l15;
        op[0]       = f2bf((oacc[qt][dt][0] + oo[0]) * r0);
        op[768]     = f2bf((oacc[qt][dt][1] + oo[1]) * r1);
        op[2 * 768] = f2bf((oacc[qt][dt][2] + oo[2]) * r2);
        op[3 * 768] = f2bf((oacc[qt][dt][3] + oo[3]) * r3);
      }
    }
  }
}

extern "C" void kernel_launch(void* const* d_in, const int* in_sizes, int n_in,
                              void* d_out, int out_size, void* d_ws, size_t ws_size,
                              hipStream_t stream) {
  const float* x      = (const float*)d_in[0];
  const float* qkv_w  = (const float*)d_in[1];
  const float* qkv_b  = (const float*)d_in[2];
  const float* proj_w = (const float*)d_in[3];
  const float* proj_b = (const float*)d_in[4];
  float* out = (float*)d_out;

  const int N = 4096, C = 768, H = 12, D = 64, C3 = 2304;
  char* ws = (char*)d_ws;
  size_t off = 0;
  u16* xb    = (u16*)(ws + off); off += (size_t)N * C * 2;       // 6.29 MB (reused as attn-out)
  u16* wqkv  = (u16*)(ws + off); off += (size_t)C3 * C * 2;      // 3.54 MB
  u16* wproj = (u16*)(ws + off); off += (size_t)C * C * 2;       // 1.18 MB
  u16* qbuf  = (u16*)(ws + off); off += (size_t)H * N * D * 2;   // 6.29 MB
  u16* kbuf  = (u16*)(ws + off); off += (size_t)H * N * D * 2;
  u16* vbuf  = (u16*)(ws + off); off += (size_t)H * N * D * 2;   // V^T [H][64][4096]
  u16* aob = xb;  // alias: xb dead after QKV GEMM

  const int na4 = N * C / 4, nb4 = C3 * C / 4, nc4 = C * C / 4;
  int ntot = na4 + nb4 + nc4;
  cast3<<<(ntot + 255) / 256, 256, 0, stream>>>(x, na4, qkv_w, nb4, proj_w, nc4, xb, wqkv, wproj);

  dim3 g1(C3 / 128, N / 128);  // 18 x 32
  gemm_bt<0><<<g1, 256, 0, stream>>>(xb, wqkv, qkv_b, qbuf, kbuf, vbuf, nullptr, C, C3);

  flash_attn<<<768, 256, 0, stream>>>(qbuf, kbuf, vbuf, aob);

  dim3 g3(C / 128, N / 128);   // 6 x 32
  gemm_bt<1><<<g3, 256, 0, stream>>>(aob, wproj, proj_b, nullptr, nullptr, nullptr, out, C, C);
}

// Round 9
// 124.501 us; speedup vs baseline: 2.0165x; 1.0675x over previous
//
#include <hip/hip_runtime.h>

// Fused attention block for MI355X (gfx950).
// x[4096,768] fp32 -> QKV bf16 GEMM -> flash attention (12 heads, D=64) -> proj GEMM -> fp32 out.
// MFMA v_mfma_f32_16x16x32_bf16 verified layouts:
//   A-frag: m=lane&15, k=quad*8+j ; B-frag: n=lane&15, k=quad*8+j ; C/D: row=quad*4+reg, col=lane&15.
// flash_attn v10 = v9 (wave split + deferred-PV pipeline + cvt_pk, proven 85.7us) with the
// P-LDS round-trip replaced by the v2-VERIFIED in-register permlane exchange:
//   S^T lane layout -> PV A-frag layout is a 4x4 quad-block transpose =
//   permlane32_swap + permlane16_swap per register pair (8 VALU ops/wave-iter, replaces
//   4 ds_write + 2 ds_read + lgkm waits; 16 KB/block-iter less LDS traffic; pl buffer freed).
//   v2 paid for this exchange on the critical path; v9's deferred-PV moved P consumption to
//   the NEXT iteration, so the exchange latency is now fully hidden.
// + s_setprio(1) around the MFMA cluster (T5: helps attn with independent blocks/CU).
// Softmax is UN-NORMALIZED (no running max: logits bounded, exp2 arg << 128); lsum reduced
// once in the epilogue. Q is pre-scaled by 8*log2(e) so p = exp2(s) directly (raw v_exp_f32).
// Lessons: v5 (no prefetch -> latency), v6 (remat), v7 (spill), v8 (LDS-BW relieved),
// v9 (chain shortened; wall now distributed VALU/LDS/sync).

typedef short bf16x8 __attribute__((ext_vector_type(8)));
typedef float f32x4 __attribute__((ext_vector_type(4)));
typedef unsigned short u16;
typedef unsigned int u32;

__device__ __forceinline__ u16 f2bf(float f) {
  u32 u = __float_as_uint(f);
  u = (u + 0x7fffu + ((u >> 16) & 1u)) >> 16;  // RNE
  return (u16)u;
}

// HW packed f32x2 -> bf16x2 (RNE; the standard fptrunc lowering on gfx950): [a low, b high]
__device__ __forceinline__ u32 cvtpk(float a, float b) {
  u32 r;
  asm("v_cvt_pk_bf16_f32 %0, %1, %2" : "=v"(r) : "v"(a), "v"(b));
  return r;
}

__device__ __forceinline__ void gload16(const void* g, void* l) {
  __builtin_amdgcn_global_load_lds(
      (const __attribute__((address_space(1))) unsigned int*)g,
      (__attribute__((address_space(3))) unsigned int*)l, 16, 0, 0);
}

// gfx950 cross-lane half-swaps (both registers updated in place); verified in v2 (passed):
// permlane32: x' = [x.q0|x.q1|y.q0|y.q1], y' = [x.q2|x.q3|y.q2|y.q3]
// permlane16: x' = [x.q0|y.q0|x.q2|y.q2], y' = [x.q1|y.q1|x.q3|y.q3]
__device__ __forceinline__ void pl32swap(u32& x, u32& y) {
  asm("v_permlane32_swap_b32 %0, %1" : "+v"(x), "+v"(y));
}
__device__ __forceinline__ void pl16swap(u32& x, u32& y) {
  asm("v_permlane16_swap_b32 %0, %1" : "+v"(x), "+v"(y));
}

// ---------------- fused fp32 -> bf16 cast of x, qkv_w, proj_w (one launch) ----------------
__global__ void cast3(const float* __restrict__ a, int na4,
                      const float* __restrict__ b, int nb4,
                      const float* __restrict__ c, int nc4,
                      u16* __restrict__ oa, u16* __restrict__ obp, u16* __restrict__ oc) {
  int i = blockIdx.x * blockDim.x + threadIdx.x;
  const float* src;
  u16* dst;
  int j = i;
  if (i < na4) { src = a; dst = oa; }
  else if (i < na4 + nb4) { src = b; dst = obp; j = i - na4; }
  else if (i < na4 + nb4 + nc4) { src = c; dst = oc; j = i - na4 - nb4; }
  else return;
  float4 v = ((const float4*)src)[j];
  ushort4 o;
  o.x = f2bf(v.x); o.y = f2bf(v.y); o.z = f2bf(v.z); o.w = f2bf(v.w);
  ((ushort4*)dst)[j] = o;
}

// ---------------- m97-style GEMM: C[M,N] = A[M,K] * B[N,K]^T + bias ----------------
// MODE 0: scatter bf16 into q/k/v. q,k: [H][4096][64] (q pre-scaled by 8*log2e); v: [H][64][4096].
// MODE 1: fp32 out[M,N] (final projection, N=768)
template <int MODE>
__global__ __launch_bounds__(256, 2) void gemm_bt(
    const u16* __restrict__ A, const u16* __restrict__ B,
    const float* __restrict__ bias,
    u16* __restrict__ qb, u16* __restrict__ kbuf, u16* __restrict__ vb,
    float* __restrict__ outp, int K, int N) {
  __shared__ __align__(16) u16 As[128 * 32];
  __shared__ __align__(16) u16 Bs[128 * 32];
  const int tid = threadIdx.x, lane = tid & 63, w = tid >> 6;
  const int wr = w >> 1, wc = w & 1, quad = lane >> 4, l15 = lane & 15;
  const int m0 = blockIdx.y * 128, n0 = blockIdx.x * 128;

  f32x4 acc[4][4];
#pragma unroll
  for (int i = 0; i < 4; ++i)
#pragma unroll
    for (int j = 0; j < 4; ++j) acc[i][j] = (f32x4){0.f, 0.f, 0.f, 0.f};

  for (int k0 = 0; k0 < K; k0 += 32) {
    __syncthreads();
#pragma unroll
    for (int i = 0; i < 2; ++i) {
      int chunk = i * 256 + w * 64 + lane;     // 512 chunks of 16B per 8KB tile
      int row = chunk >> 2, kc = chunk & 3;
      gload16(A + (size_t)(m0 + row) * K + k0 + kc * 8, (char*)As + chunk * 16);
      gload16(B + (size_t)(n0 + row) * K + k0 + kc * 8, (char*)Bs + chunk * 16);
    }
    __syncthreads();
    bf16x8 af[4], bfr[4];
#pragma unroll
    for (int mi = 0; mi < 4; ++mi)
      af[mi] = *(const bf16x8*)&As[(wr * 64 + mi * 16 + l15) * 32 + quad * 8];
#pragma unroll
    for (int ni = 0; ni < 4; ++ni)
      bfr[ni] = *(const bf16x8*)&Bs[(wc * 64 + ni * 16 + l15) * 32 + quad * 8];
#pragma unroll
    for (int mi = 0; mi < 4; ++mi)
#pragma unroll
      for (int ni = 0; ni < 4; ++ni)
        acc[mi][ni] = __builtin_amdgcn_mfma_f32_16x16x32_bf16(af[mi], bfr[ni], acc[mi][ni], 0, 0, 0);
  }

#pragma unroll
  for (int mi = 0; mi < 4; ++mi) {
    int row = m0 + wr * 64 + mi * 16 + quad * 4;
#pragma unroll
    for (int ni = 0; ni < 4; ++ni) {
      int col = n0 + wc * 64 + ni * 16 + l15;
      float bv = bias[col];
      if (MODE == 0) {
        int t = col / 768;
        int rem = col - t * 768;
        int hh = rem >> 6, d = rem & 63;
        if (t == 2) {  // V: transposed [H][64][4096]; 4 rows pack into one ushort4
          u16* dst = vb + (size_t)hh * 64 * 4096 + (size_t)d * 4096 + row;
          ushort4 pk;
          pk.x = f2bf(acc[mi][ni][0] + bv);
          pk.y = f2bf(acc[mi][ni][1] + bv);
          pk.z = f2bf(acc[mi][ni][2] + bv);
          pk.w = f2bf(acc[mi][ni][3] + bv);
          *(ushort4*)dst = pk;
        } else {
          u16* dst = (t == 0 ? qb : kbuf) + (size_t)hh * 4096 * 64 + d;
          // Q carries sqrt(D)=8 (reference quirk) AND log2(e) so attention does p=exp2(s)
          float sc = (t == 0) ? 11.541560327111707f : 1.f;
#pragma unroll
          for (int r = 0; r < 4; ++r)
            dst[(size_t)(row + r) * 64] = f2bf((acc[mi][ni][r] + bv) * sc);
        }
      } else {
#pragma unroll
        for (int r = 0; r < 4; ++r)
          outp[(size_t)(row + r) * N + col] = acc[mi][ni][r] + bv;
      }
    }
  }
}

// ---------------- flash attention v10: wave split + deferred-PV + in-register P ----------------
// 1 block = (64 q-rows, head). 4 waves: wave w = (q-half w>>1 [32 qrows], key-half w&1 [32 keys]).
// Iter t: barrier; stage t+1; K(t) ds_reads; PV(t-1) (pure-reg MFMAs under K latency); S(t);
// V(t)->regs; softmax(t) (exp2 + cvt_pk + permlane exchange -> P regs). PV(63) after the loop.
__global__ __launch_bounds__(256, 3) void flash_attn(
    const u16* __restrict__ qb, const u16* __restrict__ kb,
    const u16* __restrict__ vtg, u16* __restrict__ ob) {
  __shared__ __align__(16) u16 Ks[2][64 * 64];   // 8 KB each
  __shared__ __align__(16) u16 Vs[2][64 * 64];

  // XCD swizzle: each XCD (b&7) covers 96 consecutive work items = 1.5 heads -> K/V in its L2
  const int b = blockIdx.x;
  const int g = (b & 7) * 96 + (b >> 3);
  const int h = g >> 6;
  const int q0 = (g & 63) * 64;

  const int tid = threadIdx.x, lane = tid & 63, w = tid >> 6;
  const int quad = lane >> 4, l15 = lane & 15;
  const int qh2 = w >> 1, kh = w & 1;            // wave role: (q-half, key-half)
  const u16* qptr = qb + (size_t)h * 4096 * 64;
  const u16* kptr = kb + (size_t)h * 4096 * 64;
  const u16* vptr = vtg + (size_t)h * 64 * 4096; // [d][key]
  const int sw = l15 & 7;                        // read-side swizzle (row&7 == l15&7 for all reads)
  const int u0 = (quad ^ sw) * 8;                // K d-chunk c=0
  const int u1 = ((quad + 4) ^ sw) * 8;          // K d-chunk c=1
  const int uv = (((kh << 2) + quad) ^ sw) * 8;  // V key-chunk for this wave's key-half

  // staging: 512 chunks of 16B per tile; this thread's 2 chunks per tile
  int c0 = w * 64 + lane, c1 = 256 + w * 64 + lane;
  int r0s = c0 >> 3, j0s = ((c0 & 7) ^ (r0s & 7)) * 8;
  int r1s = c1 >> 3, j1s = ((c1 & 7) ^ (r1s & 7)) * 8;

  // Q B-frags (loop-invariant): n=qrow = q0 + qh2*32 + qt*16 + l15, k=d
  bf16x8 qf[2][2];
#pragma unroll
  for (int qt = 0; qt < 2; ++qt)
#pragma unroll
    for (int c = 0; c < 2; ++c)
      qf[qt][c] = *(const bf16x8*)&qptr[(size_t)(q0 + qh2 * 32 + qt * 16 + l15) * 64 + c * 32 + quad * 8];

  f32x4 oacc[2][4];  // O-partial[qt][dt]: row=quad*4+r (qrow), col=l15 (d); this wave's key-half only
#pragma unroll
  for (int qt = 0; qt < 2; ++qt)
#pragma unroll
    for (int dt = 0; dt < 4; ++dt) oacc[qt][dt] = (f32x4){0.f, 0.f, 0.f, 0.f};
  float lsum[2] = {0.f, 0.f};  // per-lane partial exp-sums, one per q-tile
  const f32x4 zero4 = (f32x4){0.f, 0.f, 0.f, 0.f};

  // pipeline registers: P(t) and V(t) frags carried to iteration t+1
  bf16x8 pfprev[2], vprev[4];

  // prologue: stage tile 0 into buffer 0
  gload16(kptr + (size_t)r0s * 64 + j0s, (char*)&Ks[0][0] + c0 * 16);
  gload16(kptr + (size_t)r1s * 64 + j1s, (char*)&Ks[0][0] + c1 * 16);
  gload16(vptr + (size_t)r0s * 4096 + j0s, (char*)&Vs[0][0] + c0 * 16);
  gload16(vptr + (size_t)r1s * 4096 + j1s, (char*)&Vs[0][0] + c1 * 16);

  for (int t = 0; t < 64; ++t) {
    const int buf = t & 1;
    __syncthreads();  // staging of buf complete; all waves done computing on buf^1
    if (t < 63) {     // stage tile t+1 into buf^1 (drained only at the NEXT barrier)
      int kt1 = (t + 1) * 64;
      gload16(kptr + (size_t)(kt1 + r0s) * 64 + j0s, (char*)&Ks[buf ^ 1][0] + c0 * 16);
      gload16(kptr + (size_t)(kt1 + r1s) * 64 + j1s, (char*)&Ks[buf ^ 1][0] + c1 * 16);
      gload16(vptr + (size_t)r0s * 4096 + kt1 + j0s, (char*)&Vs[buf ^ 1][0] + c0 * 16);
      gload16(vptr + (size_t)r1s * 4096 + kt1 + j1s, (char*)&Vs[buf ^ 1][0] + c1 * 16);
    }

    // K A-frags for this wave's 32-key half: m=key = kh*32 + mt*16 + l15 (issue first)
    bf16x8 kf[2][2];
#pragma unroll
    for (int mt = 0; mt < 2; ++mt) {
      const u16* kr = &Ks[buf][((kh << 5) + mt * 16 + l15) * 64];
      kf[mt][0] = *(const bf16x8*)(kr + u0);
      kf[mt][1] = *(const bf16x8*)(kr + u1);
    }

    __builtin_amdgcn_s_setprio(1);
    // PV(t-1): pure-register MFMAs — execute under the K ds_read latency
    if (t > 0) {
#pragma unroll
      for (int qt = 0; qt < 2; ++qt)
#pragma unroll
        for (int dt = 0; dt < 4; ++dt)
          oacc[qt][dt] = __builtin_amdgcn_mfma_f32_16x16x32_bf16(pfprev[qt], vprev[dt], oacc[qt][dt], 0, 0, 0);
    }

    // S^T tiles: A = K (m=key), B = Q regs (n=qrow); s already in log2 units
    // Lane holds S[key = kh*32 + mt*16 + quad*4 + r][qrow = qt*16 + l15]
    f32x4 st[2][2];  // [mt][qt]
#pragma unroll
    for (int mt = 0; mt < 2; ++mt)
#pragma unroll
      for (int qt = 0; qt < 2; ++qt) {
        f32x4 z = __builtin_amdgcn_mfma_f32_16x16x32_bf16(kf[mt][0], qf[qt][0], zero4, 0, 0, 0);
        st[mt][qt] = __builtin_amdgcn_mfma_f32_16x16x32_bf16(kf[mt][1], qf[qt][1], z, 0, 0, 0);
      }
    __builtin_amdgcn_s_setprio(0);

    // V^T B-frags (this key-half) -> carried regs; LGKM overlaps the exp VALU below
#pragma unroll
    for (int dt = 0; dt < 4; ++dt)
      vprev[dt] = *(const bf16x8*)(&Vs[buf][(dt * 16 + l15) * 64] + uv);

    // max-free softmax + in-register P redistribution (v2-verified quad-block transpose).
    // Lane (q,l15) holds S[key=16mt+4q+r][qrow=l15]; PV A-frag needs P[qrow=l15][key=8q'+j].
#pragma unroll
    for (int qt = 0; qt < 2; ++qt) {
      float p00 = __builtin_amdgcn_exp2f(st[0][qt][0]);
      float p01 = __builtin_amdgcn_exp2f(st[0][qt][1]);
      float p02 = __builtin_amdgcn_exp2f(st[0][qt][2]);
      float p03 = __builtin_amdgcn_exp2f(st[0][qt][3]);
      float p10 = __builtin_amdgcn_exp2f(st[1][qt][0]);
      float p11 = __builtin_amdgcn_exp2f(st[1][qt][1]);
      float p12 = __builtin_amdgcn_exp2f(st[1][qt][2]);
      float p13 = __builtin_amdgcn_exp2f(st[1][qt][3]);
      lsum[qt] += ((p00 + p01) + (p02 + p03)) + ((p10 + p11) + (p12 + p13));
      u32 x0 = cvtpk(p00, p01), x1 = cvtpk(p02, p03);  // mt=0 word pairs
      u32 y0 = cvtpk(p10, p11), y1 = cvtpk(p12, p13);  // mt=1 word pairs
      pl32swap(x0, y0); pl16swap(x0, y0);  // x0 = frag word0, y0 = frag word2
      pl32swap(x1, y1); pl16swap(x1, y1);  // x1 = frag word1, y1 = frag word3
      union { u32 u[4]; bf16x8 v; } pu;
      pu.u[0] = x0; pu.u[1] = x1; pu.u[2] = y0; pu.u[3] = y1;
      pfprev[qt] = pu.v;
    }
  }

  // drain the pipeline: PV(63)
#pragma unroll
  for (int qt = 0; qt < 2; ++qt)
#pragma unroll
    for (int dt = 0; dt < 4; ++dt)
      oacc[qt][dt] = __builtin_amdgcn_mfma_f32_16x16x32_bf16(pfprev[qt], vprev[dt], oacc[qt][dt], 0, 0, 0);

  // ---- epilogue: reduce across quads, then across key-half waves via dead K/V LDS ----
  __syncthreads();  // all waves done reading Ks/Vs; safe to reuse as reduction scratch
#pragma unroll
  for (int qt = 0; qt < 2; ++qt) {
    lsum[qt] += __shfl_xor(lsum[qt], 16);
    lsum[qt] += __shfl_xor(lsum[qt], 32);  // now per-qrow(l15) sum over this wave's 32 keys
  }
  float* ored = (float*)&Ks[0][0];  // 2qh x 2qt x 4dt x 64lane x f32x4 = 16 KB (= both Ks bufs)
  float* lred = (float*)&Vs[0][0];  // 2qh x 2qt x 16 floats
  if (kh == 1) {
#pragma unroll
    for (int qt = 0; qt < 2; ++qt) {
#pragma unroll
      for (int dt = 0; dt < 4; ++dt)
        *(f32x4*)&ored[((((qh2 * 2 + qt) * 4 + dt) * 64) + lane) * 4] = oacc[qt][dt];
      if (quad == 0) lred[(qh2 * 2 + qt) * 16 + l15] = lsum[qt];
    }
  }
  __syncthreads();
  if (kh == 0) {
#pragma unroll
    for (int qt = 0; qt < 2; ++qt) {
      float linv = 1.f / (lsum[qt] + lred[(qh2 * 2 + qt) * 16 + l15]);  // per qrow = l15
      float r0 = __shfl(linv, quad * 4 + 0);
      float r1 = __shfl(linv, quad * 4 + 1);
      float r2 = __shfl(linv, quad * 4 + 2);
      float r3 = __shfl(linv, quad * 4 + 3);
#pragma unroll
      for (int dt = 0; dt < 4; ++dt) {
        f32x4 oo = *(const f32x4*)&ored[((((qh2 * 2 + qt) * 4 + dt) * 64) + lane) * 4];
        int row = q0 + qh2 * 32 + qt * 16 + quad * 4;
        u16* op = ob + (size_t)row * 768 + h * 64 + dt * 16 + l15;
        op[0]       = f2bf((oacc[qt][dt][0] + oo[0]) * r0);
        op[768]     = f2bf((oacc[qt][dt][1] + oo[1]) * r1);
        op[2 * 768] = f2bf((oacc[qt][dt][2] + oo[2]) * r2);
        op[3 * 768] = f2bf((oacc[qt][dt][3] + oo[3]) * r3);
      }
    }
  }
}

extern "C" void kernel_launch(void* const* d_in, const int* in_sizes, int n_in,
                              void* d_out, int out_size, void* d_ws, size_t ws_size,
                              hipStream_t stream) {
  const float* x      = (const float*)d_in[0];
  const float* qkv_w  = (const float*)d_in[1];
  const float* qkv_b  = (const float*)d_in[2];
  const float* proj_w = (const float*)d_in[3];
  const float* proj_b = (const float*)d_in[4];
  float* out = (float*)d_out;

  const int N = 4096, C = 768, H = 12, D = 64, C3 = 2304;
  char* ws = (char*)d_ws;
  size_t off = 0;
  u16* xb    = (u16*)(ws + off); off += (size_t)N * C * 2;       // 6.29 MB (reused as attn-out)
  u16* wqkv  = (u16*)(ws + off); off += (size_t)C3 * C * 2;      // 3.54 MB
  u16* wproj = (u16*)(ws + off); off += (size_t)C * C * 2;       // 1.18 MB
  u16* qbuf  = (u16*)(ws + off); off += (size_t)H * N * D * 2;   // 6.29 MB
  u16* kbuf  = (u16*)(ws + off); off += (size_t)H * N * D * 2;
  u16* vbuf  = (u16*)(ws + off); off += (size_t)H * N * D * 2;   // V^T [H][64][4096]
  u16* aob = xb;  // alias: xb dead after QKV GEMM

  const int na4 = N * C / 4, nb4 = C3 * C / 4, nc4 = C * C / 4;
  int ntot = na4 + nb4 + nc4;
  cast3<<<(ntot + 255) / 256, 256, 0, stream>>>(x, na4, qkv_w, nb4, proj_w, nc4, xb, wqkv, wproj);

  dim3 g1(C3 / 128, N / 128);  // 18 x 32
  gemm_bt<0><<<g1, 256, 0, stream>>>(xb, wqkv, qkv_b, qbuf, kbuf, vbuf, nullptr, C, C3);

  flash_attn<<<768, 256, 0, stream>>>(qbuf, kbuf, vbuf, aob);

  dim3 g3(C / 128, N / 128);   // 6 x 32
  gemm_bt<1><<<g3, 256, 0, stream>>>(aob, wproj, proj_b, nullptr, nullptr, nullptr, out, C, C);
}

// Round 10
// 117.313 us; speedup vs baseline: 2.1400x; 1.0613x over previous
//
#include <hip/hip_runtime.h>

// Fused attention block for MI355X (gfx950).
// x[4096,768] fp32 -> QKV bf16 GEMM -> flash attention (12 heads, D=64) -> proj GEMM -> fp32 out.
// MFMA v_mfma_f32_16x16x32_bf16 verified layouts:
//   A-frag: m=lane&15, k=quad*8+j ; B-frag: n=lane&15, k=quad*8+j ; C/D: row=quad*4+reg, col=lane&15.
// flash_attn v11 = v10 (wave split + deferred-PV + in-register permlane P, proven 79.3us) +
//   - lsum via ones-MFMA: mfma(P, ones) accumulates exact per-qrow key-sums in C-layout
//     (row=quad*4+r = qrow, all cols identical) -> removes 14 VALU adds/iter AND all epilogue
//     lsum shuffles. 2 extra deferred MFMAs/iter (~10 cyc MFMA pipe, was 27% util).
//   - 2x unrolled t-loop (buf literal) + staging addresses as incremented base pointers.
// gemm_bt MODE 1 (projection): TM=64 retile -> grid 384 (was 192 = 0.75 blocks/CU with 64 CUs
//   idle and 1 wave/SIMD; latency-naked). MODE 0 unchanged (TM=128).
// Softmax is UN-NORMALIZED (no running max: logits bounded, exp2 arg << 128).
// Q is pre-scaled by 8*log2(e) so p = exp2(s) directly (raw v_exp_f32).
// Lessons: v5 (no prefetch -> latency), v6 (remat), v7 (spill), v8 (LDS-BW relieved),
// v9/v10 (chain shortened; wall = issue/overlap at 3 waves/SIMD, TLP grid-capped).

typedef short bf16x8 __attribute__((ext_vector_type(8)));
typedef float f32x4 __attribute__((ext_vector_type(4)));
typedef unsigned short u16;
typedef unsigned int u32;

__device__ __forceinline__ u16 f2bf(float f) {
  u32 u = __float_as_uint(f);
  u = (u + 0x7fffu + ((u >> 16) & 1u)) >> 16;  // RNE
  return (u16)u;
}

// HW packed f32x2 -> bf16x2 (RNE; the standard fptrunc lowering on gfx950): [a low, b high]
__device__ __forceinline__ u32 cvtpk(float a, float b) {
  u32 r;
  asm("v_cvt_pk_bf16_f32 %0, %1, %2" : "=v"(r) : "v"(a), "v"(b));
  return r;
}

__device__ __forceinline__ void gload16(const void* g, void* l) {
  __builtin_amdgcn_global_load_lds(
      (const __attribute__((address_space(1))) unsigned int*)g,
      (__attribute__((address_space(3))) unsigned int*)l, 16, 0, 0);
}

// gfx950 cross-lane half-swaps (both registers updated in place); verified in v2/v10 (passed):
__device__ __forceinline__ void pl32swap(u32& x, u32& y) {
  asm("v_permlane32_swap_b32 %0, %1" : "+v"(x), "+v"(y));
}
__device__ __forceinline__ void pl16swap(u32& x, u32& y) {
  asm("v_permlane16_swap_b32 %0, %1" : "+v"(x), "+v"(y));
}

// ---------------- fused fp32 -> bf16 cast of x, qkv_w, proj_w (one launch) ----------------
__global__ void cast3(const float* __restrict__ a, int na4,
                      const float* __restrict__ b, int nb4,
                      const float* __restrict__ c, int nc4,
                      u16* __restrict__ oa, u16* __restrict__ obp, u16* __restrict__ oc) {
  int i = blockIdx.x * blockDim.x + threadIdx.x;
  const float* src;
  u16* dst;
  int j = i;
  if (i < na4) { src = a; dst = oa; }
  else if (i < na4 + nb4) { src = b; dst = obp; j = i - na4; }
  else if (i < na4 + nb4 + nc4) { src = c; dst = oc; j = i - na4 - nb4; }
  else return;
  float4 v = ((const float4*)src)[j];
  ushort4 o;
  o.x = f2bf(v.x); o.y = f2bf(v.y); o.z = f2bf(v.z); o.w = f2bf(v.w);
  ((ushort4*)dst)[j] = o;
}

// ---------------- m97-style GEMM: C[M,N] = A[M,K] * B[N,K]^T + bias ----------------
// MODE 0: scatter bf16 into q/k/v. q,k: [H][4096][64] (q pre-scaled by 8*log2e); v: [H][64][4096].
//         TM=128 (grid 18x32 = 576 blocks).
// MODE 1: fp32 out[M,N] (final projection, N=768). TM=64 -> grid 6x64 = 384 blocks (TLP fix).
template <int MODE>
__global__ __launch_bounds__(256, 2) void gemm_bt(
    const u16* __restrict__ A, const u16* __restrict__ B,
    const float* __restrict__ bias,
    u16* __restrict__ qb, u16* __restrict__ kbuf, u16* __restrict__ vb,
    float* __restrict__ outp, int K, int N) {
  constexpr int TM = (MODE == 1) ? 64 : 128;  // M tile
  constexpr int MI = TM / 32;                 // M frags per wave (wave strip = TM/2 rows)
  __shared__ __align__(16) u16 As[TM * 32];
  __shared__ __align__(16) u16 Bs[128 * 32];
  const int tid = threadIdx.x, lane = tid & 63, w = tid >> 6;
  const int wr = w >> 1, wc = w & 1, quad = lane >> 4, l15 = lane & 15;
  const int m0 = blockIdx.y * TM, n0 = blockIdx.x * 128;

  f32x4 acc[MI][4];
#pragma unroll
  for (int i = 0; i < MI; ++i)
#pragma unroll
    for (int j = 0; j < 4; ++j) acc[i][j] = (f32x4){0.f, 0.f, 0.f, 0.f};

  for (int k0 = 0; k0 < K; k0 += 32) {
    __syncthreads();
#pragma unroll
    for (int i = 0; i < TM / 64; ++i) {      // A tile: TM*4 chunks of 16B
      int chunk = i * 256 + tid;
      int row = chunk >> 2, kc = chunk & 3;
      gload16(A + (size_t)(m0 + row) * K + k0 + kc * 8, (char*)As + chunk * 16);
    }
#pragma unroll
    for (int i = 0; i < 2; ++i) {            // B tile: 512 chunks of 16B
      int chunk = i * 256 + tid;
      int row = chunk >> 2, kc = chunk & 3;
      gload16(B + (size_t)(n0 + row) * K + k0 + kc * 8, (char*)Bs + chunk * 16);
    }
    __syncthreads();
    bf16x8 af[MI], bfr[4];
#pragma unroll
    for (int mi = 0; mi < MI; ++mi)
      af[mi] = *(const bf16x8*)&As[(wr * (TM / 2) + mi * 16 + l15) * 32 + quad * 8];
#pragma unroll
    for (int ni = 0; ni < 4; ++ni)
      bfr[ni] = *(const bf16x8*)&Bs[(wc * 64 + ni * 16 + l15) * 32 + quad * 8];
#pragma unroll
    for (int mi = 0; mi < MI; ++mi)
#pragma unroll
      for (int ni = 0; ni < 4; ++ni)
        acc[mi][ni] = __builtin_amdgcn_mfma_f32_16x16x32_bf16(af[mi], bfr[ni], acc[mi][ni], 0, 0, 0);
  }

#pragma unroll
  for (int mi = 0; mi < MI; ++mi) {
    int row = m0 + wr * (TM / 2) + mi * 16 + quad * 4;
#pragma unroll
    for (int ni = 0; ni < 4; ++ni) {
      int col = n0 + wc * 64 + ni * 16 + l15;
      float bv = bias[col];
      if (MODE == 0) {
        int t = col / 768;
        int rem = col - t * 768;
        int hh = rem >> 6, d = rem & 63;
        if (t == 2) {  // V: transposed [H][64][4096]; 4 rows pack into one ushort4
          u16* dst = vb + (size_t)hh * 64 * 4096 + (size_t)d * 4096 + row;
          ushort4 pk;
          pk.x = f2bf(acc[mi][ni][0] + bv);
          pk.y = f2bf(acc[mi][ni][1] + bv);
          pk.z = f2bf(acc[mi][ni][2] + bv);
          pk.w = f2bf(acc[mi][ni][3] + bv);
          *(ushort4*)dst = pk;
        } else {
          u16* dst = (t == 0 ? qb : kbuf) + (size_t)hh * 4096 * 64 + d;
          // Q carries sqrt(D)=8 (reference quirk) AND log2(e) so attention does p=exp2(s)
          float sc = (t == 0) ? 11.541560327111707f : 1.f;
#pragma unroll
          for (int r = 0; r < 4; ++r)
            dst[(size_t)(row + r) * 64] = f2bf((acc[mi][ni][r] + bv) * sc);
        }
      } else {
#pragma unroll
        for (int r = 0; r < 4; ++r)
          outp[(size_t)(row + r) * N + col] = acc[mi][ni][r] + bv;
      }
    }
  }
}

// ---------------- flash attention v11: wave split + deferred-PV + ones-MFMA lsum ----------------
// 1 block = (64 q-rows, head). 4 waves: wave w = (q-half w>>1 [32 qrows], key-half w&1 [32 keys]).
// Iter t: barrier; stage t+1 (incremented base ptrs); K(t) ds_reads; {PV(t-1) + lsum-MFMA(t-1)}
// under K latency; S(t); V(t)->regs; softmax(t) (exp2 + cvt_pk + permlane -> P regs).
__global__ __launch_bounds__(256, 3) void flash_attn(
    const u16* __restrict__ qb, const u16* __restrict__ kb,
    const u16* __restrict__ vtg, u16* __restrict__ ob) {
  __shared__ __align__(16) u16 Ks[2][64 * 64];   // 8 KB each
  __shared__ __align__(16) u16 Vs[2][64 * 64];

  // XCD swizzle: each XCD (b&7) covers 96 consecutive work items = 1.5 heads -> K/V in its L2
  const int b = blockIdx.x;
  const int g = (b & 7) * 96 + (b >> 3);
  const int h = g >> 6;
  const int q0 = (g & 63) * 64;

  const int tid = threadIdx.x, lane = tid & 63, w = tid >> 6;
  const int quad = lane >> 4, l15 = lane & 15;
  const int qh2 = w >> 1, kh = w & 1;            // wave role: (q-half, key-half)
  const u16* qptr = qb + (size_t)h * 4096 * 64;
  const u16* kptr = kb + (size_t)h * 4096 * 64;
  const u16* vptr = vtg + (size_t)h * 64 * 4096; // [d][key]
  const int sw = l15 & 7;                        // read-side swizzle (row&7 == l15&7 for all reads)
  const int u0 = (quad ^ sw) * 8;                // K d-chunk c=0
  const int u1 = ((quad + 4) ^ sw) * 8;          // K d-chunk c=1
  const int uv = (((kh << 2) + quad) ^ sw) * 8;  // V key-chunk for this wave's key-half

  // staging: 512 chunks of 16B per tile; this thread's 2 chunks per tile
  int c0 = w * 64 + lane, c1 = 256 + w * 64 + lane;
  int r0s = c0 >> 3, j0s = ((c0 & 7) ^ (r0s & 7)) * 8;
  int r1s = c1 >> 3, j1s = ((c1 & 7) ^ (r1s & 7)) * 8;

  // Q B-frags (loop-invariant): n=qrow = q0 + qh2*32 + qt*16 + l15, k=d
  bf16x8 qf[2][2];
#pragma unroll
  for (int qt = 0; qt < 2; ++qt)
#pragma unroll
    for (int c = 0; c < 2; ++c)
      qf[qt][c] = *(const bf16x8*)&qptr[(size_t)(q0 + qh2 * 32 + qt * 16 + l15) * 64 + c * 32 + quad * 8];

  f32x4 oacc[2][4];  // O-partial[qt][dt]: row=quad*4+r (qrow), col=l15 (d); this wave's key-half only
  f32x4 lacc[2];     // lsum[qt]: row=quad*4+r (qrow), all cols identical (ones-MFMA output)
#pragma unroll
  for (int qt = 0; qt < 2; ++qt) {
    lacc[qt] = (f32x4){0.f, 0.f, 0.f, 0.f};
#pragma unroll
    for (int dt = 0; dt < 4; ++dt) oacc[qt][dt] = (f32x4){0.f, 0.f, 0.f, 0.f};
  }
  const f32x4 zero4 = (f32x4){0.f, 0.f, 0.f, 0.f};
  bf16x8 onesf;
#pragma unroll
  for (int i = 0; i < 8; ++i) onesf[i] = (short)0x3F80;  // bf16 1.0

  // pipeline registers: P(t) and V(t) frags carried to iteration t+1
  bf16x8 pfprev[2], vprev[4];

  // prologue: stage tile 0 into buffer 0
  gload16(kptr + (size_t)r0s * 64 + j0s, (char*)&Ks[0][0] + c0 * 16);
  gload16(kptr + (size_t)r1s * 64 + j1s, (char*)&Ks[0][0] + c1 * 16);
  gload16(vptr + (size_t)r0s * 4096 + j0s, (char*)&Vs[0][0] + c0 * 16);
  gload16(vptr + (size_t)r1s * 4096 + j1s, (char*)&Vs[0][0] + c1 * 16);

  // staging source pointers, pre-offset to tile 1; incremented each staged tile
  const u16* ks0 = kptr + (size_t)(64 + r0s) * 64 + j0s;
  const u16* ks1 = kptr + (size_t)(64 + r1s) * 64 + j1s;
  const u16* vs0 = vptr + (size_t)r0s * 4096 + 64 + j0s;
  const u16* vs1 = vptr + (size_t)r1s * 4096 + 64 + j1s;

  auto body = [&](int t, int buf) {
    __syncthreads();  // staging of buf complete; all waves done computing on buf^1
    if (t < 63) {     // stage tile t+1 into buf^1 (drained only at the NEXT barrier)
      gload16(ks0, (char*)&Ks[buf ^ 1][0] + c0 * 16);
      gload16(ks1, (char*)&Ks[buf ^ 1][0] + c1 * 16);
      gload16(vs0, (char*)&Vs[buf ^ 1][0] + c0 * 16);
      gload16(vs1, (char*)&Vs[buf ^ 1][0] + c1 * 16);
      ks0 += 64 * 64; ks1 += 64 * 64; vs0 += 64; vs1 += 64;
    }

    // K A-frags for this wave's 32-key half: m=key = kh*32 + mt*16 + l15 (issue first)
    bf16x8 kf[2][2];
#pragma unroll
    for (int mt = 0; mt < 2; ++mt) {
      const u16* kr = &Ks[buf][((kh << 5) + mt * 16 + l15) * 64];
      kf[mt][0] = *(const bf16x8*)(kr + u0);
      kf[mt][1] = *(const bf16x8*)(kr + u1);
    }

    __builtin_amdgcn_s_setprio(1);
    // PV(t-1) + lsum(t-1): pure-register MFMAs — execute under the K ds_read latency
    if (t > 0) {
#pragma unroll
      for (int qt = 0; qt < 2; ++qt) {
#pragma unroll
        for (int dt = 0; dt < 4; ++dt)
          oacc[qt][dt] = __builtin_amdgcn_mfma_f32_16x16x32_bf16(pfprev[qt], vprev[dt], oacc[qt][dt], 0, 0, 0);
        lacc[qt] = __builtin_amdgcn_mfma_f32_16x16x32_bf16(pfprev[qt], onesf, lacc[qt], 0, 0, 0);
      }
    }

    // S^T tiles: A = K (m=key), B = Q regs (n=qrow); s already in log2 units
    f32x4 st[2][2];  // [mt][qt]
#pragma unroll
    for (int mt = 0; mt < 2; ++mt)
#pragma unroll
      for (int qt = 0; qt < 2; ++qt) {
        f32x4 z = __builtin_amdgcn_mfma_f32_16x16x32_bf16(kf[mt][0], qf[qt][0], zero4, 0, 0, 0);
        st[mt][qt] = __builtin_amdgcn_mfma_f32_16x16x32_bf16(kf[mt][1], qf[qt][1], z, 0, 0, 0);
      }
    __builtin_amdgcn_s_setprio(0);

    // V^T B-frags (this key-half) -> carried regs; LGKM overlaps the exp VALU below
#pragma unroll
    for (int dt = 0; dt < 4; ++dt)
      vprev[dt] = *(const bf16x8*)(&Vs[buf][(dt * 16 + l15) * 64] + uv);

    // max-free softmax + in-register P redistribution (verified quad-block transpose)
#pragma unroll
    for (int qt = 0; qt < 2; ++qt) {
      float p00 = __builtin_amdgcn_exp2f(st[0][qt][0]);
      float p01 = __builtin_amdgcn_exp2f(st[0][qt][1]);
      float p02 = __builtin_amdgcn_exp2f(st[0][qt][2]);
      float p03 = __builtin_amdgcn_exp2f(st[0][qt][3]);
      float p10 = __builtin_amdgcn_exp2f(st[1][qt][0]);
      float p11 = __builtin_amdgcn_exp2f(st[1][qt][1]);
      float p12 = __builtin_amdgcn_exp2f(st[1][qt][2]);
      float p13 = __builtin_amdgcn_exp2f(st[1][qt][3]);
      u32 x0 = cvtpk(p00, p01), x1 = cvtpk(p02, p03);  // mt=0 word pairs
      u32 y0 = cvtpk(p10, p11), y1 = cvtpk(p12, p13);  // mt=1 word pairs
      pl32swap(x0, y0); pl16swap(x0, y0);  // x0 = frag word0, y0 = frag word2
      pl32swap(x1, y1); pl16swap(x1, y1);  // x1 = frag word1, y1 = frag word3
      union { u32 u[4]; bf16x8 v; } pu;
      pu.u[0] = x0; pu.u[1] = x1; pu.u[2] = y0; pu.u[3] = y1;
      pfprev[qt] = pu.v;
    }
  };

  for (int tt = 0; tt < 32; ++tt) {
    body(2 * tt, 0);
    body(2 * tt + 1, 1);
  }

  // drain the pipeline: PV(63) + lsum(63)
#pragma unroll
  for (int qt = 0; qt < 2; ++qt) {
#pragma unroll
    for (int dt = 0; dt < 4; ++dt)
      oacc[qt][dt] = __builtin_amdgcn_mfma_f32_16x16x32_bf16(pfprev[qt], vprev[dt], oacc[qt][dt], 0, 0, 0);
    lacc[qt] = __builtin_amdgcn_mfma_f32_16x16x32_bf16(pfprev[qt], onesf, lacc[qt], 0, 0, 0);
  }

  // ---- epilogue: combine key-half partials via dead K/V LDS (no shuffles needed) ----
  // lacc[qt][r] = sum_p P[qrow = qt*16 + quad*4 + r][all 32 keys of this half] (all lanes agree)
  __syncthreads();  // all waves done reading Ks/Vs; safe to reuse as reduction scratch
  float* ored = (float*)&Ks[0][0];  // 2qh x 2qt x 4dt x 64lane x f32x4 = 16 KB (= both Ks bufs)
  float* lred = (float*)&Vs[0][0];  // 2qh x 2qt x 16 floats
  if (kh == 1) {
#pragma unroll
    for (int qt = 0; qt < 2; ++qt) {
#pragma unroll
      for (int dt = 0; dt < 4; ++dt)
        *(f32x4*)&ored[((((qh2 * 2 + qt) * 4 + dt) * 64) + lane) * 4] = oacc[qt][dt];
      if (l15 == 0) {
#pragma unroll
        for (int r = 0; r < 4; ++r)
          lred[(qh2 * 2 + qt) * 16 + quad * 4 + r] = lacc[qt][r];
      }
    }
  }
  __syncthreads();
  if (kh == 0) {
#pragma unroll
    for (int qt = 0; qt < 2; ++qt) {
      f32x4 linv;
#pragma unroll
      for (int r = 0; r < 4; ++r)
        linv[r] = 1.f / (lacc[qt][r] + lred[(qh2 * 2 + qt) * 16 + quad * 4 + r]);
#pragma unroll
      for (int dt = 0; dt < 4; ++dt) {
        f32x4 oo = *(const f32x4*)&ored[((((qh2 * 2 + qt) * 4 + dt) * 64) + lane) * 4];
        int row = q0 + qh2 * 32 + qt * 16 + quad * 4;
        u16* op = ob + (size_t)row * 768 + h * 64 + dt * 16 + l15;
        op[0]       = f2bf((oacc[qt][dt][0] + oo[0]) * linv[0]);
        op[768]     = f2bf((oacc[qt][dt][1] + oo[1]) * linv[1]);
        op[2 * 768] = f2bf((oacc[qt][dt][2] + oo[2]) * linv[2]);
        op[3 * 768] = f2bf((oacc[qt][dt][3] + oo[3]) * linv[3]);
      }
    }
  }
}

extern "C" void kernel_launch(void* const* d_in, const int* in_sizes, int n_in,
                              void* d_out, int out_size, void* d_ws, size_t ws_size,
                              hipStream_t stream) {
  const float* x      = (const float*)d_in[0];
  const float* qkv_w  = (const float*)d_in[1];
  const float* qkv_b  = (const float*)d_in[2];
  const float* proj_w = (const float*)d_in[3];
  const float* proj_b = (const float*)d_in[4];
  float* out = (float*)d_out;

  const int N = 4096, C = 768, H = 12, D = 64, C3 = 2304;
  char* ws = (char*)d_ws;
  size_t off = 0;
  u16* xb    = (u16*)(ws + off); off += (size_t)N * C * 2;       // 6.29 MB (reused as attn-out)
  u16* wqkv  = (u16*)(ws + off); off += (size_t)C3 * C * 2;      // 3.54 MB
  u16* wproj = (u16*)(ws + off); off += (size_t)C * C * 2;       // 1.18 MB
  u16* qbuf  = (u16*)(ws + off); off += (size_t)H * N * D * 2;   // 6.29 MB
  u16* kbuf  = (u16*)(ws + off); off += (size_t)H * N * D * 2;
  u16* vbuf  = (u16*)(ws + off); off += (size_t)H * N * D * 2;   // V^T [H][64][4096]
  u16* aob = xb;  // alias: xb dead after QKV GEMM

  const int na4 = N * C / 4, nb4 = C3 * C / 4, nc4 = C * C / 4;
  int ntot = na4 + nb4 + nc4;
  cast3<<<(ntot + 255) / 256, 256, 0, stream>>>(x, na4, qkv_w, nb4, proj_w, nc4, xb, wqkv, wproj);

  dim3 g1(C3 / 128, N / 128);  // 18 x 32
  gemm_bt<0><<<g1, 256, 0, stream>>>(xb, wqkv, qkv_b, qbuf, kbuf, vbuf, nullptr, C, C3);

  flash_attn<<<768, 256, 0, stream>>>(qbuf, kbuf, vbuf, aob);

  dim3 g3(C / 128, N / 64);    // 6 x 64 = 384 blocks (TM=64 retile)
  gemm_bt<1><<<g3, 256, 0, stream>>>(aob, wproj, proj_b, nullptr, nullptr, nullptr, out, C, C);
}